// Round 2
// baseline (2204.072 us; speedup 1.0000x reference)
//
#include <hip/hip_runtime.h>

#define NF 64  // hidden width (all layers after the first GEMM)

// ---------------- degree / normalization ----------------
__global__ void k_deg_init(float* __restrict__ deg, int n) {
    int i = blockIdx.x * blockDim.x + threadIdx.x;
    if (i < n) deg[i] = 1.0f;  // self-loop
}

__global__ void k_deg_count(const int* __restrict__ dst, float* __restrict__ deg, int E) {
    int e = blockIdx.x * blockDim.x + threadIdx.x;
    if (e < E) atomicAdd(&deg[dst[e]], 1.0f);
}

__global__ void k_rsqrt(float* __restrict__ deg, int n) {
    int i = blockIdx.x * blockDim.x + threadIdx.x;
    if (i < n) deg[i] = rsqrtf(deg[i]);
}

// ---------------- GEMM: out[n,64] = act(A[n,K]) @ W[K,64] ----------------
// act = identity (bias_in==null) or relu(A + bias_in) applied on load.
// Block: 256 threads, 64 rows x 64 cols tile, 4x4 outputs/thread.
template<int K>
__global__ __launch_bounds__(256) void k_gemm(const float* __restrict__ A,
                                              const float* __restrict__ W,
                                              const float* __restrict__ bias_in,
                                              float* __restrict__ out, int n) {
    __shared__ float sW[K * NF];    // [k][col]
    __shared__ float sxT[K * 64];   // transposed A tile: [k][row]
    const int tid = threadIdx.x;
    const int row_base = blockIdx.x * 64;

    for (int i = tid * 4; i < K * NF; i += 256 * 4)
        *(float4*)&sW[i] = *(const float4*)&W[i];

    constexpr int KV = K / 4;
    for (int v = tid; v < 64 * KV; v += 256) {
        int r  = v / KV;
        int kv = v - r * KV;
        int rg = row_base + r;
        float4 val = make_float4(0.f, 0.f, 0.f, 0.f);
        if (rg < n) val = *(const float4*)&A[(size_t)rg * K + kv * 4];
        if (bias_in) {
            val.x = fmaxf(val.x + bias_in[kv * 4 + 0], 0.f);
            val.y = fmaxf(val.y + bias_in[kv * 4 + 1], 0.f);
            val.z = fmaxf(val.z + bias_in[kv * 4 + 2], 0.f);
            val.w = fmaxf(val.w + bias_in[kv * 4 + 3], 0.f);
        }
        sxT[(kv * 4 + 0) * 64 + r] = val.x;
        sxT[(kv * 4 + 1) * 64 + r] = val.y;
        sxT[(kv * 4 + 2) * 64 + r] = val.z;
        sxT[(kv * 4 + 3) * 64 + r] = val.w;
    }
    __syncthreads();

    const int tx = tid & 15, ty = tid >> 4;
    const int c0 = tx * 4, r0 = ty * 4;
    float acc[4][4] = {{0.f}};
    #pragma unroll 4
    for (int k = 0; k < K; ++k) {
        const float4 xv = *(const float4*)&sxT[k * 64 + r0];
        const float4 wv = *(const float4*)&sW[k * 64 + c0];
        const float xs[4] = {xv.x, xv.y, xv.z, xv.w};
        const float ws[4] = {wv.x, wv.y, wv.z, wv.w};
        #pragma unroll
        for (int i = 0; i < 4; ++i)
            #pragma unroll
            for (int j = 0; j < 4; ++j)
                acc[i][j] += xs[i] * ws[j];
    }

    #pragma unroll
    for (int i = 0; i < 4; ++i) {
        int r = row_base + r0 + i;
        if (r < n) {
            float4 o = make_float4(acc[i][0], acc[i][1], acc[i][2], acc[i][3]);
            *(float4*)&out[(size_t)r * NF + c0] = o;
        }
    }
}

// ---------------- self-loop init: out[i,:] = h[i,:] * dis[i]^2 ----------------
__global__ void k_self(const float* __restrict__ h, const float* __restrict__ dis,
                       float* __restrict__ out, int n) {
    int idx = blockIdx.x * blockDim.x + threadIdx.x;  // over n*16 float4s
    if (idx >= n * 16) return;
    int i = idx >> 4;
    float d = dis[i];
    float s = d * d;
    float4 v = *(const float4*)&h[(size_t)idx * 4];
    v.x *= s; v.y *= s; v.z *= s; v.w *= s;
    *(float4*)&out[(size_t)idx * 4] = v;
}

// ---------------- edge scatter: out[dst,:] += h[src,:]*dis[src]*dis[dst] ----------------
// 16 threads per edge, 4 channels each (float4 gather + 4 scalar atomics).
__global__ void k_scatter(const int* __restrict__ src, const int* __restrict__ dst,
                          const float* __restrict__ dis,
                          const float* __restrict__ h, float* __restrict__ out, int E) {
    int idx = blockIdx.x * blockDim.x + threadIdx.x;
    int e = idx >> 4;
    if (e >= E) return;
    int part = idx & 15;
    int s = src[e];
    int d = dst[e];
    float nrm = dis[s] * dis[d];
    float4 hv = *(const float4*)&h[(size_t)s * NF + part * 4];
    float* o = &out[(size_t)d * NF + part * 4];
    atomicAdd(o + 0, hv.x * nrm);
    atomicAdd(o + 1, hv.y * nrm);
    atomicAdd(o + 2, hv.z * nrm);
    atomicAdd(o + 3, hv.w * nrm);
}

// ---------------- head: out[i] = dot(relu(agg[i,:]+b2), W3) + b3 ----------------
__global__ void k_final(const float* __restrict__ agg, const float* __restrict__ b2,
                        const float* __restrict__ W3, const float* __restrict__ b3,
                        float* __restrict__ out, int n) {
    int i = blockIdx.x * (blockDim.x >> 6) + (threadIdx.x >> 6);
    int lane = threadIdx.x & 63;
    if (i >= n) return;
    float v = fmaxf(agg[(size_t)i * NF + lane] + b2[lane], 0.f) * W3[lane];
    #pragma unroll
    for (int off = 32; off > 0; off >>= 1) v += __shfl_down(v, off);
    if (lane == 0) out[i] = v + b3[0];
}

extern "C" void kernel_launch(void* const* d_in, const int* in_sizes, int n_in,
                              void* d_out, int out_size, void* d_ws, size_t ws_size,
                              hipStream_t stream) {
    const float* x  = (const float*)d_in[0];
    const int*   ei = (const int*)d_in[1];   // int32: JAX x64-disabled downcasts int64
    const float* W1 = (const float*)d_in[2];
    const float* b1 = (const float*)d_in[3];
    const float* W2 = (const float*)d_in[4];
    const float* b2 = (const float*)d_in[5];
    const float* W3 = (const float*)d_in[6];
    const float* b3 = (const float*)d_in[7];
    float* out = (float*)d_out;

    const int n = out_size;            // 100000 nodes
    const int E = in_sizes[1] / 2;     // 1.2M edges
    const int* src = ei;
    const int* dst = ei + E;

    float* dis  = (float*)d_ws;
    float* bufA = dis + ((n + 255) & ~255);
    float* bufB = bufA + (size_t)n * NF;

    const int B = 256;

    // normalization coefficients
    k_deg_init<<<(n + B - 1) / B, B, 0, stream>>>(dis, n);
    k_deg_count<<<(E + B - 1) / B, B, 0, stream>>>(dst, dis, E);
    k_rsqrt<<<(n + B - 1) / B, B, 0, stream>>>(dis, n);

    // ----- layer 1 -----
    k_gemm<128><<<(n + 63) / 64, B, 0, stream>>>(x, W1, nullptr, bufA, n);
    k_self<<<(n * 16 + B - 1) / B, B, 0, stream>>>(bufA, dis, bufB, n);
    k_scatter<<<(int)(((size_t)E * 16 + B - 1) / B), B, 0, stream>>>(src, dst, dis, bufA, bufB, E);

    // ----- layer 2 (relu(agg1+b1) fused into GEMM load) -----
    k_gemm<64><<<(n + 63) / 64, B, 0, stream>>>(bufB, W2, b1, bufA, n);
    k_self<<<(n * 16 + B - 1) / B, B, 0, stream>>>(bufA, dis, bufB, n);
    k_scatter<<<(int)(((size_t)E * 16 + B - 1) / B), B, 0, stream>>>(src, dst, dis, bufA, bufB, E);

    // ----- head -----
    k_final<<<(n + 3) / 4, B, 0, stream>>>(bufB, b2, W3, b3, out, n);
}

// Round 3
// 330.070 us; speedup vs baseline: 6.6776x; 6.6776x over previous
//
#include <hip/hip_runtime.h>

#define NF 64  // hidden width

// ---------------- CSR build ----------------
__global__ void k_zero(int* __restrict__ cnt, int* __restrict__ gbase, int n) {
    int i = blockIdx.x * blockDim.x + threadIdx.x;
    if (i < n) cnt[i] = 0;
    if (i == 0) *gbase = 0;
}

__global__ void k_hist(const int* __restrict__ dst, int* __restrict__ cnt, int E) {
    int e = blockIdx.x * blockDim.x + threadIdx.x;
    if (e < E) atomicAdd(&cnt[dst[e]], 1);
}

// block of 256 threads scans 1024 counts; block base via atomic (ranges need not
// be in index order, only disjoint). Also emits dis = rsqrt(deg+1) and cursor=start.
__global__ __launch_bounds__(256) void k_offsets(const int* __restrict__ cnt,
                                                 int* __restrict__ start,
                                                 int* __restrict__ cursor,
                                                 float* __restrict__ dis,
                                                 int* __restrict__ gbase, int n) {
    __shared__ int tsum[256];
    __shared__ int bbase;
    const int t = threadIdx.x;
    const int i0 = blockIdx.x * 1024 + t * 4;
    int c[4]; int s = 0;
    #pragma unroll
    for (int k = 0; k < 4; ++k) { c[k] = (i0 + k < n) ? cnt[i0 + k] : 0; s += c[k]; }
    tsum[t] = s; __syncthreads();
    for (int off = 1; off < 256; off <<= 1) {
        int u = (t >= off) ? tsum[t - off] : 0;
        __syncthreads();
        tsum[t] += u;
        __syncthreads();
    }
    if (t == 0) bbase = atomicAdd(gbase, tsum[255]);
    __syncthreads();
    int run = bbase + tsum[t] - s;
    #pragma unroll
    for (int k = 0; k < 4; ++k) {
        int i = i0 + k;
        if (i < n) {
            start[i] = run; cursor[i] = run;
            dis[i] = rsqrtf((float)(c[k] + 1));
            run += c[k];
        }
    }
}

__global__ void k_fill(const int* __restrict__ src, const int* __restrict__ dst,
                       int* __restrict__ cursor, int* __restrict__ adj, int E) {
    int e = blockIdx.x * blockDim.x + threadIdx.x;
    if (e < E) {
        int pos = atomicAdd(&cursor[dst[e]], 1);
        adj[pos] = src[e];
    }
}

// ---------------- GEMM: out[n,64] = act(A[n,K]) @ W[K,64] * dis[row] ----------------
// act = identity (bias_in==null) or relu(A + bias_in) applied on load.
template<int K>
__global__ __launch_bounds__(256) void k_gemm(const float* __restrict__ A,
                                              const float* __restrict__ W,
                                              const float* __restrict__ bias_in,
                                              const float* __restrict__ dis,
                                              float* __restrict__ out, int n) {
    __shared__ float sW[K * NF];    // [k][col]
    __shared__ float sxT[K * 64];   // transposed A tile: [k][row]
    const int tid = threadIdx.x;
    const int row_base = blockIdx.x * 64;

    for (int i = tid * 4; i < K * NF; i += 256 * 4)
        *(float4*)&sW[i] = *(const float4*)&W[i];

    constexpr int KV = K / 4;
    for (int v = tid; v < 64 * KV; v += 256) {
        int r  = v / KV;
        int kv = v - r * KV;
        int rg = row_base + r;
        float4 val = make_float4(0.f, 0.f, 0.f, 0.f);
        if (rg < n) val = *(const float4*)&A[(size_t)rg * K + kv * 4];
        if (bias_in) {
            val.x = fmaxf(val.x + bias_in[kv * 4 + 0], 0.f);
            val.y = fmaxf(val.y + bias_in[kv * 4 + 1], 0.f);
            val.z = fmaxf(val.z + bias_in[kv * 4 + 2], 0.f);
            val.w = fmaxf(val.w + bias_in[kv * 4 + 3], 0.f);
        }
        sxT[(kv * 4 + 0) * 64 + r] = val.x;
        sxT[(kv * 4 + 1) * 64 + r] = val.y;
        sxT[(kv * 4 + 2) * 64 + r] = val.z;
        sxT[(kv * 4 + 3) * 64 + r] = val.w;
    }
    __syncthreads();

    const int tx = tid & 15, ty = tid >> 4;
    const int c0 = tx * 4, r0 = ty * 4;
    float acc[4][4] = {{0.f}};
    #pragma unroll 4
    for (int k = 0; k < K; ++k) {
        const float4 xv = *(const float4*)&sxT[k * 64 + r0];
        const float4 wv = *(const float4*)&sW[k * 64 + c0];
        const float xs[4] = {xv.x, xv.y, xv.z, xv.w};
        const float ws[4] = {wv.x, wv.y, wv.z, wv.w};
        #pragma unroll
        for (int i = 0; i < 4; ++i)
            #pragma unroll
            for (int j = 0; j < 4; ++j)
                acc[i][j] += xs[i] * ws[j];
    }

    #pragma unroll
    for (int i = 0; i < 4; ++i) {
        int r = row_base + r0 + i;
        if (r < n) {
            float sc = dis[r];
            float4 o = make_float4(acc[i][0] * sc, acc[i][1] * sc,
                                   acc[i][2] * sc, acc[i][3] * sc);
            *(float4*)&out[(size_t)r * NF + c0] = o;
        }
    }
}

// ---------------- gather: out[d,:] = dis[d] * (g[d,:] + sum g[adj,:]) ----------------
// one 64-lane wave per node; lane = feature channel.
__global__ __launch_bounds__(256) void k_gather(const float* __restrict__ g,
                                                const int* __restrict__ adj,
                                                const int* __restrict__ start,
                                                const int* __restrict__ endp,
                                                const float* __restrict__ dis,
                                                float* __restrict__ out, int n) {
    int node = blockIdx.x * 4 + (threadIdx.x >> 6);
    int lane = threadIdx.x & 63;
    if (node >= n) return;
    int s = start[node], e = endp[node];
    float a0 = g[(size_t)node * NF + lane];   // self-loop term
    float a1 = 0.f, a2 = 0.f, a3 = 0.f;
    for (int base = s; base < e; base += 64) {
        int m = e - base; if (m > 64) m = 64;
        int idx = (lane < m) ? adj[base + lane] : 0;
        int j = 0;
        for (; j + 3 < m; j += 4) {
            int u0 = __shfl(idx, j),     u1 = __shfl(idx, j + 1);
            int u2 = __shfl(idx, j + 2), u3 = __shfl(idx, j + 3);
            a0 += g[(size_t)u0 * NF + lane];
            a1 += g[(size_t)u1 * NF + lane];
            a2 += g[(size_t)u2 * NF + lane];
            a3 += g[(size_t)u3 * NF + lane];
        }
        for (; j < m; ++j) {
            int u = __shfl(idx, j);
            a0 += g[(size_t)u * NF + lane];
        }
    }
    out[(size_t)node * NF + lane] = (a0 + a1 + a2 + a3) * dis[node];
}

// ---------------- head: out[i] = dot(relu(agg[i,:]+b2), W3) + b3 ----------------
__global__ void k_final(const float* __restrict__ agg, const float* __restrict__ b2,
                        const float* __restrict__ W3, const float* __restrict__ b3,
                        float* __restrict__ out, int n) {
    int i = blockIdx.x * (blockDim.x >> 6) + (threadIdx.x >> 6);
    int lane = threadIdx.x & 63;
    if (i >= n) return;
    float v = fmaxf(agg[(size_t)i * NF + lane] + b2[lane], 0.f) * W3[lane];
    #pragma unroll
    for (int off = 32; off > 0; off >>= 1) v += __shfl_down(v, off);
    if (lane == 0) out[i] = v + b3[0];
}

extern "C" void kernel_launch(void* const* d_in, const int* in_sizes, int n_in,
                              void* d_out, int out_size, void* d_ws, size_t ws_size,
                              hipStream_t stream) {
    const float* x  = (const float*)d_in[0];
    const int*   ei = (const int*)d_in[1];   // int32 (JAX x64-disabled)
    const float* W1 = (const float*)d_in[2];
    const float* b1 = (const float*)d_in[3];
    const float* W2 = (const float*)d_in[4];
    const float* b2 = (const float*)d_in[5];
    const float* W3 = (const float*)d_in[6];
    const float* b3 = (const float*)d_in[7];
    float* out = (float*)d_out;

    const int n = out_size;            // 100000
    const int E = in_sizes[1] / 2;     // 1200000
    const int* src = ei;
    const int* dst = ei + E;
    const int ns = (n + 255) & ~255;   // 100352

    char* w = (char*)d_ws;
    float* dis   = (float*)w;                         w += (size_t)ns * 4;
    float* bufA  = (float*)w;                         w += (size_t)n * NF * 4;
    float* bufB  = (float*)w;                         w += (size_t)n * NF * 4;
    int*   cnt   = (int*)w;                           w += (size_t)ns * 4;
    int*   start = (int*)w;                           w += (size_t)ns * 4;
    int*   cursor= (int*)w;                           w += (size_t)ns * 4;
    int*   adj   = (int*)w;                           w += (size_t)E * 4;
    int*   gbase = (int*)w;

    const int B = 256;

    // CSR build + normalization
    k_zero<<<ns / B, B, 0, stream>>>(cnt, gbase, ns);
    k_hist<<<(E + B - 1) / B, B, 0, stream>>>(dst, cnt, E);
    k_offsets<<<(n + 1023) / 1024, B, 0, stream>>>(cnt, start, cursor, dis, gbase, n);
    k_fill<<<(E + B - 1) / B, B, 0, stream>>>(src, dst, cursor, adj, E);

    // ----- layer 1 -----
    k_gemm<128><<<(n + 63) / 64, B, 0, stream>>>(x, W1, nullptr, dis, bufA, n);
    k_gather<<<(n + 3) / 4, B, 0, stream>>>(bufA, adj, start, cursor, dis, bufB, n);

    // ----- layer 2 -----
    k_gemm<64><<<(n + 63) / 64, B, 0, stream>>>(bufB, W2, b1, dis, bufA, n);
    k_gather<<<(n + 3) / 4, B, 0, stream>>>(bufA, adj, start, cursor, dis, bufB, n);

    // ----- head -----
    k_final<<<(n + 3) / 4, B, 0, stream>>>(bufB, b2, W3, b3, out, n);
}

// Round 4
// 257.367 us; speedup vs baseline: 8.5639x; 1.2825x over previous
//
#include <hip/hip_runtime.h>

#define NF 64
#define NBKMAX 512   // buckets of 256 nodes; n=100K -> 391 buckets
#define CHUNK 4096

// ---------------- bucket-radix CSR build ----------------
__global__ void k_zero(int* __restrict__ p, int m) {
    int i = blockIdx.x * blockDim.x + threadIdx.x;
    if (i < m) p[i] = 0;
}

__global__ __launch_bounds__(256) void k_bhist(const int* __restrict__ dst,
                                               int* __restrict__ bcnt, int E, int nbk) {
    __shared__ int h[NBKMAX];
    for (int i = threadIdx.x; i < nbk; i += 256) h[i] = 0;
    __syncthreads();
    int stride = gridDim.x * 256;
    for (int i = blockIdx.x * 256 + threadIdx.x; i < E; i += stride)
        atomicAdd(&h[((unsigned)dst[i]) >> 8], 1);
    __syncthreads();
    for (int i = threadIdx.x; i < nbk; i += 256) {
        int c = h[i];
        if (c) atomicAdd(&bcnt[i], c);
    }
}

__global__ __launch_bounds__(512) void k_bscan(const int* __restrict__ bcnt,
                                               int* __restrict__ bbase, int* __restrict__ bcur,
                                               int* __restrict__ start, int nbk, int n, int E) {
    __shared__ int s[512];
    int t = threadIdx.x;
    int v = (t < nbk) ? bcnt[t] : 0;
    s[t] = v; __syncthreads();
    for (int off = 1; off < 512; off <<= 1) {
        int u = (t >= off) ? s[t - off] : 0;
        __syncthreads();
        s[t] += u;
        __syncthreads();
    }
    int exc = s[t] - v;
    if (t < nbk) { bbase[t] = exc; bcur[t] = exc; }
    if (t == 0) { bbase[nbk] = E; start[n] = E; }
}

// stage a chunk in LDS, reserve per-bucket ranges with one global atomic each,
// write (src,dst) pairs clustered per-WG -> near-sequential global writes.
__global__ __launch_bounds__(256) void k_bscatter(const int* __restrict__ src,
                                                  const int* __restrict__ dst,
                                                  int* __restrict__ bcur,
                                                  uint2* __restrict__ pairs, int E, int nbk) {
    __shared__ int hist[NBKMAX];
    __shared__ int base[NBKMAX];
    __shared__ uint2 stage[CHUNK];
    int e0 = blockIdx.x * CHUNK;
    int cnt = E - e0; if (cnt > CHUNK) cnt = CHUNK;
    for (int i = threadIdx.x; i < nbk; i += 256) hist[i] = 0;
    __syncthreads();
    for (int i = threadIdx.x; i < cnt; i += 256) {
        int s = src[e0 + i], d = dst[e0 + i];
        stage[i] = make_uint2((unsigned)s, (unsigned)d);
        atomicAdd(&hist[((unsigned)d) >> 8], 1);
    }
    __syncthreads();
    for (int i = threadIdx.x; i < nbk; i += 256) {
        int c = hist[i];
        base[i] = c ? atomicAdd(&bcur[i], c) : 0;
        hist[i] = 0;   // reuse as local cursor
    }
    __syncthreads();
    for (int i = threadIdx.x; i < cnt; i += 256) {
        uint2 p = stage[i];
        int b = p.y >> 8;
        int off = atomicAdd(&hist[b], 1);
        pairs[base[b] + off] = p;
    }
}

// one WG per bucket: LDS counting sort into the bucket's contiguous adj region;
// emits per-node start (globally monotone) and dis = rsqrt(deg+1).
__global__ __launch_bounds__(256) void k_bsort(const uint2* __restrict__ pairs,
                                               const int* __restrict__ bbase,
                                               int* __restrict__ start, int* __restrict__ adj,
                                               float* __restrict__ dis, int n) {
    __shared__ int cnt[256];
    __shared__ int cur[256];
    int b  = blockIdx.x;
    int nb = b << 8;
    int nn = n - nb; if (nn > 256) nn = 256;
    int eb = bbase[b];
    int ec = bbase[b + 1] - eb;
    int t  = threadIdx.x;
    cnt[t] = 0;
    __syncthreads();
    for (int i = t; i < ec; i += 256)
        atomicAdd(&cnt[pairs[eb + i].y & 255], 1);
    __syncthreads();
    int v = cnt[t];
    __syncthreads();
    for (int off = 1; off < 256; off <<= 1) {    // inclusive scan
        int u = (t >= off) ? cnt[t - off] : 0;
        __syncthreads();
        cnt[t] += u;
        __syncthreads();
    }
    int exc = cnt[t] - v;
    if (t < nn) {
        start[nb + t] = eb + exc;
        dis[nb + t]   = rsqrtf((float)(v + 1));
    }
    cur[t] = exc;
    __syncthreads();
    for (int i = t; i < ec; i += 256) {
        uint2 p = pairs[eb + i];
        int off = atomicAdd(&cur[p.y & 255], 1);
        adj[eb + off] = (int)p.x;
    }
}

// ---------------- GEMM: out[n,64] = act(A[n,K]) @ W[K,64] * dis[row] ----------------
template<int K>
__global__ __launch_bounds__(256) void k_gemm(const float* __restrict__ A,
                                              const float* __restrict__ W,
                                              const float* __restrict__ bias_in,
                                              const float* __restrict__ dis,
                                              float* __restrict__ out, int n) {
    __shared__ float sW[K * NF];
    __shared__ float sxT[K * 64];
    const int tid = threadIdx.x;
    const int row_base = blockIdx.x * 64;

    for (int i = tid * 4; i < K * NF; i += 256 * 4)
        *(float4*)&sW[i] = *(const float4*)&W[i];

    constexpr int KV = K / 4;
    for (int v = tid; v < 64 * KV; v += 256) {
        int r  = v / KV;
        int kv = v - r * KV;
        int rg = row_base + r;
        float4 val = make_float4(0.f, 0.f, 0.f, 0.f);
        if (rg < n) val = *(const float4*)&A[(size_t)rg * K + kv * 4];
        if (bias_in) {
            val.x = fmaxf(val.x + bias_in[kv * 4 + 0], 0.f);
            val.y = fmaxf(val.y + bias_in[kv * 4 + 1], 0.f);
            val.z = fmaxf(val.z + bias_in[kv * 4 + 2], 0.f);
            val.w = fmaxf(val.w + bias_in[kv * 4 + 3], 0.f);
        }
        sxT[(kv * 4 + 0) * 64 + r] = val.x;
        sxT[(kv * 4 + 1) * 64 + r] = val.y;
        sxT[(kv * 4 + 2) * 64 + r] = val.z;
        sxT[(kv * 4 + 3) * 64 + r] = val.w;
    }
    __syncthreads();

    const int tx = tid & 15, ty = tid >> 4;
    const int c0 = tx * 4, r0 = ty * 4;
    float acc[4][4] = {{0.f}};
    #pragma unroll 4
    for (int k = 0; k < K; ++k) {
        const float4 xv = *(const float4*)&sxT[k * 64 + r0];
        const float4 wv = *(const float4*)&sW[k * 64 + c0];
        const float xs[4] = {xv.x, xv.y, xv.z, xv.w};
        const float ws[4] = {wv.x, wv.y, wv.z, wv.w};
        #pragma unroll
        for (int i = 0; i < 4; ++i)
            #pragma unroll
            for (int j = 0; j < 4; ++j)
                acc[i][j] += xs[i] * ws[j];
    }

    #pragma unroll
    for (int i = 0; i < 4; ++i) {
        int r = row_base + r0 + i;
        if (r < n) {
            float sc = dis[r];
            *(float4*)&out[(size_t)r * NF + c0] =
                make_float4(acc[i][0] * sc, acc[i][1] * sc, acc[i][2] * sc, acc[i][3] * sc);
        }
    }
}

// ---------------- gather: out[d,:] = dis[d] * (g[d,:] + sum g[adj,:]) ----------------
__global__ __launch_bounds__(256) void k_gather(const float* __restrict__ g,
                                                const int* __restrict__ adj,
                                                const int* __restrict__ start,
                                                const float* __restrict__ dis,
                                                float* __restrict__ out, int n) {
    int node = blockIdx.x * 4 + (threadIdx.x >> 6);
    int lane = threadIdx.x & 63;
    if (node >= n) return;
    int s = start[node], e = start[node + 1];
    float a0 = g[(size_t)node * NF + lane];
    float a1 = 0.f, a2 = 0.f, a3 = 0.f;
    for (int base = s; base < e; base += 64) {
        int m = e - base; if (m > 64) m = 64;
        int idx = (lane < m) ? adj[base + lane] : 0;
        int j = 0;
        for (; j + 3 < m; j += 4) {
            int u0 = __shfl(idx, j),     u1 = __shfl(idx, j + 1);
            int u2 = __shfl(idx, j + 2), u3 = __shfl(idx, j + 3);
            a0 += g[(size_t)u0 * NF + lane];
            a1 += g[(size_t)u1 * NF + lane];
            a2 += g[(size_t)u2 * NF + lane];
            a3 += g[(size_t)u3 * NF + lane];
        }
        for (; j < m; ++j) {
            int u = __shfl(idx, j);
            a0 += g[(size_t)u * NF + lane];
        }
    }
    out[(size_t)node * NF + lane] = (a0 + a1 + a2 + a3) * dis[node];
}

// ---------------- gather + head fused: out[i] = dot(relu(agg+b2), W3) + b3 ----------------
__global__ __launch_bounds__(256) void k_gather_final(const float* __restrict__ g,
                                                      const int* __restrict__ adj,
                                                      const int* __restrict__ start,
                                                      const float* __restrict__ dis,
                                                      const float* __restrict__ b2,
                                                      const float* __restrict__ W3,
                                                      const float* __restrict__ b3,
                                                      float* __restrict__ out, int n) {
    int node = blockIdx.x * 4 + (threadIdx.x >> 6);
    int lane = threadIdx.x & 63;
    if (node >= n) return;
    int s = start[node], e = start[node + 1];
    float a0 = g[(size_t)node * NF + lane];
    float a1 = 0.f, a2 = 0.f, a3 = 0.f;
    for (int base = s; base < e; base += 64) {
        int m = e - base; if (m > 64) m = 64;
        int idx = (lane < m) ? adj[base + lane] : 0;
        int j = 0;
        for (; j + 3 < m; j += 4) {
            int u0 = __shfl(idx, j),     u1 = __shfl(idx, j + 1);
            int u2 = __shfl(idx, j + 2), u3 = __shfl(idx, j + 3);
            a0 += g[(size_t)u0 * NF + lane];
            a1 += g[(size_t)u1 * NF + lane];
            a2 += g[(size_t)u2 * NF + lane];
            a3 += g[(size_t)u3 * NF + lane];
        }
        for (; j < m; ++j) {
            int u = __shfl(idx, j);
            a0 += g[(size_t)u * NF + lane];
        }
    }
    float val = (a0 + a1 + a2 + a3) * dis[node];
    float v = fmaxf(val + b2[lane], 0.f) * W3[lane];
    #pragma unroll
    for (int off = 32; off > 0; off >>= 1) v += __shfl_down(v, off);
    if (lane == 0) out[node] = v + b3[0];
}

extern "C" void kernel_launch(void* const* d_in, const int* in_sizes, int n_in,
                              void* d_out, int out_size, void* d_ws, size_t ws_size,
                              hipStream_t stream) {
    const float* x  = (const float*)d_in[0];
    const int*   ei = (const int*)d_in[1];   // int32 (JAX x64-disabled)
    const float* W1 = (const float*)d_in[2];
    const float* b1 = (const float*)d_in[3];
    const float* W2 = (const float*)d_in[4];
    const float* b2 = (const float*)d_in[5];
    const float* W3 = (const float*)d_in[6];
    const float* b3 = (const float*)d_in[7];
    float* out = (float*)d_out;

    const int n = out_size;           // 100000
    const int E = in_sizes[1] / 2;    // 1200000
    const int* src = ei;
    const int* dst = ei + E;
    const int ns  = (n + 255) & ~255;
    const int nbk = (n + 255) >> 8;   // 391 buckets

    char* w = (char*)d_ws;
    float* dis   = (float*)w;  w += (size_t)ns * 4;
    int*   start = (int*)w;    w += (size_t)(ns + 256) * 4;
    int*   adj   = (int*)w;    w += (size_t)E * 4;
    int*   bcnt  = (int*)w;    w += NBKMAX * 4;
    int*   bbase = (int*)w;    w += (NBKMAX + 1) * 4;
    int*   bcur  = (int*)w;    w += NBKMAX * 4;
    float* bufA  = (float*)w;  w += (size_t)n * NF * 4;
    float* bufB  = (float*)w;  // 25.6 MB; pairs (9.6 MB) aliased here, dead before gather1
    uint2* pairs = (uint2*)bufB;

    const int B = 256;

    // CSR build (bucketed radix, no global random scatter)
    k_zero<<<(nbk + B - 1) / B, B, 0, stream>>>(bcnt, nbk);
    k_bhist<<<512, B, 0, stream>>>(dst, bcnt, E, nbk);
    k_bscan<<<1, 512, 0, stream>>>(bcnt, bbase, bcur, start, nbk, n, E);
    k_bscatter<<<(E + CHUNK - 1) / CHUNK, B, 0, stream>>>(src, dst, bcur, pairs, E, nbk);
    k_bsort<<<nbk, B, 0, stream>>>(pairs, bbase, start, adj, dis, n);

    // ----- layer 1 -----
    k_gemm<128><<<(n + 63) / 64, B, 0, stream>>>(x, W1, nullptr, dis, bufA, n);
    k_gather<<<(n + 3) / 4, B, 0, stream>>>(bufA, adj, start, dis, bufB, n);

    // ----- layer 2 + head -----
    k_gemm<64><<<(n + 63) / 64, B, 0, stream>>>(bufB, W2, b1, dis, bufA, n);
    k_gather_final<<<(n + 3) / 4, B, 0, stream>>>(bufA, adj, start, dis, b2, W3, b3, out, n);
}

// Round 5
// 227.623 us; speedup vs baseline: 9.6830x; 1.1307x over previous
//
#include <hip/hip_runtime.h>

#define NF 64
#define NBKMAX 512   // buckets of 256 nodes; n=100K -> 391 buckets
#define CHUNK 4096

// bf16 helpers (RNE)
__device__ __forceinline__ unsigned short f2bf(float f) {
    union { float f; unsigned u; } c; c.f = f;
    unsigned u = c.u;
    return (unsigned short)((u + 0x7FFFu + ((u >> 16) & 1u)) >> 16);
}
__device__ __forceinline__ float bf2f(unsigned short v) {
    union { unsigned u; float f; } c; c.u = ((unsigned)v) << 16;
    return c.f;
}

// ---------------- bucket-radix CSR build ----------------
__global__ void k_zero(int* __restrict__ p, int m) {
    int i = blockIdx.x * blockDim.x + threadIdx.x;
    if (i < m) p[i] = 0;
}

__global__ __launch_bounds__(256) void k_bhist(const int* __restrict__ dst,
                                               int* __restrict__ bcnt, int E, int nbk) {
    __shared__ int h[NBKMAX];
    for (int i = threadIdx.x; i < nbk; i += 256) h[i] = 0;
    __syncthreads();
    int stride = gridDim.x * 256;
    for (int i = blockIdx.x * 256 + threadIdx.x; i < E; i += stride)
        atomicAdd(&h[((unsigned)dst[i]) >> 8], 1);
    __syncthreads();
    for (int i = threadIdx.x; i < nbk; i += 256) {
        int c = h[i];
        if (c) atomicAdd(&bcnt[i], c);
    }
}

__global__ __launch_bounds__(512) void k_bscan(const int* __restrict__ bcnt,
                                               int* __restrict__ bbase, int* __restrict__ bcur,
                                               int* __restrict__ start, int nbk, int n, int E) {
    __shared__ int s[512];
    int t = threadIdx.x;
    int v = (t < nbk) ? bcnt[t] : 0;
    s[t] = v; __syncthreads();
    for (int off = 1; off < 512; off <<= 1) {
        int u = (t >= off) ? s[t - off] : 0;
        __syncthreads();
        s[t] += u;
        __syncthreads();
    }
    int exc = s[t] - v;
    if (t < nbk) { bbase[t] = exc; bcur[t] = exc; }
    if (t == 0) { bbase[nbk] = E; start[n] = E; }
}

__global__ __launch_bounds__(256) void k_bscatter(const int* __restrict__ src,
                                                  const int* __restrict__ dst,
                                                  int* __restrict__ bcur,
                                                  uint2* __restrict__ pairs, int E, int nbk) {
    __shared__ int hist[NBKMAX];
    __shared__ int base[NBKMAX];
    __shared__ uint2 stage[CHUNK];
    int e0 = blockIdx.x * CHUNK;
    int cnt = E - e0; if (cnt > CHUNK) cnt = CHUNK;
    for (int i = threadIdx.x; i < nbk; i += 256) hist[i] = 0;
    __syncthreads();
    for (int i = threadIdx.x; i < cnt; i += 256) {
        int s = src[e0 + i], d = dst[e0 + i];
        stage[i] = make_uint2((unsigned)s, (unsigned)d);
        atomicAdd(&hist[((unsigned)d) >> 8], 1);
    }
    __syncthreads();
    for (int i = threadIdx.x; i < nbk; i += 256) {
        int c = hist[i];
        base[i] = c ? atomicAdd(&bcur[i], c) : 0;
        hist[i] = 0;   // reuse as local cursor
    }
    __syncthreads();
    for (int i = threadIdx.x; i < cnt; i += 256) {
        uint2 p = stage[i];
        int b = p.y >> 8;
        int off = atomicAdd(&hist[b], 1);
        pairs[base[b] + off] = p;
    }
}

__global__ __launch_bounds__(256) void k_bsort(const uint2* __restrict__ pairs,
                                               const int* __restrict__ bbase,
                                               int* __restrict__ start, int* __restrict__ adj,
                                               float* __restrict__ dis, int n) {
    __shared__ int cnt[256];
    __shared__ int cur[256];
    int b  = blockIdx.x;
    int nb = b << 8;
    int nn = n - nb; if (nn > 256) nn = 256;
    int eb = bbase[b];
    int ec = bbase[b + 1] - eb;
    int t  = threadIdx.x;
    cnt[t] = 0;
    __syncthreads();
    for (int i = t; i < ec; i += 256)
        atomicAdd(&cnt[pairs[eb + i].y & 255], 1);
    __syncthreads();
    int v = cnt[t];
    __syncthreads();
    for (int off = 1; off < 256; off <<= 1) {
        int u = (t >= off) ? cnt[t - off] : 0;
        __syncthreads();
        cnt[t] += u;
        __syncthreads();
    }
    int exc = cnt[t] - v;
    if (t < nn) {
        start[nb + t] = eb + exc;
        dis[nb + t]   = rsqrtf((float)(v + 1));
    }
    cur[t] = exc;
    __syncthreads();
    for (int i = t; i < ec; i += 256) {
        uint2 p = pairs[eb + i];
        int off = atomicAdd(&cur[p.y & 255], 1);
        adj[eb + off] = (int)p.x;
    }
}

// ---------------- GEMM: gbf16[n,64] = (act(A[n,K]) @ W[K,64]) * dis[row] ----------------
template<int K>
__global__ __launch_bounds__(256) void k_gemm(const float* __restrict__ A,
                                              const float* __restrict__ W,
                                              const float* __restrict__ bias_in,
                                              const float* __restrict__ dis,
                                              unsigned short* __restrict__ out, int n) {
    __shared__ float sW[K * NF];
    __shared__ float sxT[K * 64];
    const int tid = threadIdx.x;
    const int row_base = blockIdx.x * 64;

    for (int i = tid * 4; i < K * NF; i += 256 * 4)
        *(float4*)&sW[i] = *(const float4*)&W[i];

    constexpr int KV = K / 4;
    for (int v = tid; v < 64 * KV; v += 256) {
        int r  = v / KV;
        int kv = v - r * KV;
        int rg = row_base + r;
        float4 val = make_float4(0.f, 0.f, 0.f, 0.f);
        if (rg < n) val = *(const float4*)&A[(size_t)rg * K + kv * 4];
        if (bias_in) {
            val.x = fmaxf(val.x + bias_in[kv * 4 + 0], 0.f);
            val.y = fmaxf(val.y + bias_in[kv * 4 + 1], 0.f);
            val.z = fmaxf(val.z + bias_in[kv * 4 + 2], 0.f);
            val.w = fmaxf(val.w + bias_in[kv * 4 + 3], 0.f);
        }
        sxT[(kv * 4 + 0) * 64 + r] = val.x;
        sxT[(kv * 4 + 1) * 64 + r] = val.y;
        sxT[(kv * 4 + 2) * 64 + r] = val.z;
        sxT[(kv * 4 + 3) * 64 + r] = val.w;
    }
    __syncthreads();

    const int tx = tid & 15, ty = tid >> 4;
    const int c0 = tx * 4, r0 = ty * 4;
    float acc[4][4] = {{0.f}};
    #pragma unroll 4
    for (int k = 0; k < K; ++k) {
        const float4 xv = *(const float4*)&sxT[k * 64 + r0];
        const float4 wv = *(const float4*)&sW[k * 64 + c0];
        const float xs[4] = {xv.x, xv.y, xv.z, xv.w};
        const float ws[4] = {wv.x, wv.y, wv.z, wv.w};
        #pragma unroll
        for (int i = 0; i < 4; ++i)
            #pragma unroll
            for (int j = 0; j < 4; ++j)
                acc[i][j] += xs[i] * ws[j];
    }

    #pragma unroll
    for (int i = 0; i < 4; ++i) {
        int r = row_base + r0 + i;
        if (r < n) {
            float sc = dis[r];
            ushort4 o;
            o.x = f2bf(acc[i][0] * sc);
            o.y = f2bf(acc[i][1] * sc);
            o.z = f2bf(acc[i][2] * sc);
            o.w = f2bf(acc[i][3] * sc);
            *(ushort4*)&out[(size_t)r * NF + c0] = o;
        }
    }
}

// ---------------- gather: out[d,:] = dis[d] * (g[d,:] + sum g[adj,:]) ----------------
// g is bf16 (128B/row per wave), accumulate fp32, write fp32.
__global__ __launch_bounds__(256) void k_gather(const unsigned short* __restrict__ g,
                                                const int* __restrict__ adj,
                                                const int* __restrict__ start,
                                                const float* __restrict__ dis,
                                                float* __restrict__ out, int n) {
    int node = blockIdx.x * 4 + (threadIdx.x >> 6);
    int lane = threadIdx.x & 63;
    if (node >= n) return;
    int s = start[node], e = start[node + 1];
    float a0 = bf2f(g[(size_t)node * NF + lane]);
    float a1 = 0.f, a2 = 0.f, a3 = 0.f;
    for (int base = s; base < e; base += 64) {
        int m = e - base; if (m > 64) m = 64;
        int idx = (lane < m) ? adj[base + lane] : 0;
        int j = 0;
        for (; j + 3 < m; j += 4) {
            int u0 = __shfl(idx, j),     u1 = __shfl(idx, j + 1);
            int u2 = __shfl(idx, j + 2), u3 = __shfl(idx, j + 3);
            a0 += bf2f(g[(size_t)u0 * NF + lane]);
            a1 += bf2f(g[(size_t)u1 * NF + lane]);
            a2 += bf2f(g[(size_t)u2 * NF + lane]);
            a3 += bf2f(g[(size_t)u3 * NF + lane]);
        }
        for (; j < m; ++j) {
            int u = __shfl(idx, j);
            a0 += bf2f(g[(size_t)u * NF + lane]);
        }
    }
    out[(size_t)node * NF + lane] = (a0 + a1 + a2 + a3) * dis[node];
}

// ---------------- gather + head fused ----------------
__global__ __launch_bounds__(256) void k_gather_final(const unsigned short* __restrict__ g,
                                                      const int* __restrict__ adj,
                                                      const int* __restrict__ start,
                                                      const float* __restrict__ dis,
                                                      const float* __restrict__ b2,
                                                      const float* __restrict__ W3,
                                                      const float* __restrict__ b3,
                                                      float* __restrict__ out, int n) {
    int node = blockIdx.x * 4 + (threadIdx.x >> 6);
    int lane = threadIdx.x & 63;
    if (node >= n) return;
    int s = start[node], e = start[node + 1];
    float a0 = bf2f(g[(size_t)node * NF + lane]);
    float a1 = 0.f, a2 = 0.f, a3 = 0.f;
    for (int base = s; base < e; base += 64) {
        int m = e - base; if (m > 64) m = 64;
        int idx = (lane < m) ? adj[base + lane] : 0;
        int j = 0;
        for (; j + 3 < m; j += 4) {
            int u0 = __shfl(idx, j),     u1 = __shfl(idx, j + 1);
            int u2 = __shfl(idx, j + 2), u3 = __shfl(idx, j + 3);
            a0 += bf2f(g[(size_t)u0 * NF + lane]);
            a1 += bf2f(g[(size_t)u1 * NF + lane]);
            a2 += bf2f(g[(size_t)u2 * NF + lane]);
            a3 += bf2f(g[(size_t)u3 * NF + lane]);
        }
        for (; j < m; ++j) {
            int u = __shfl(idx, j);
            a0 += bf2f(g[(size_t)u * NF + lane]);
        }
    }
    float val = (a0 + a1 + a2 + a3) * dis[node];
    float v = fmaxf(val + b2[lane], 0.f) * W3[lane];
    #pragma unroll
    for (int off = 32; off > 0; off >>= 1) v += __shfl_down(v, off);
    if (lane == 0) out[node] = v + b3[0];
}

extern "C" void kernel_launch(void* const* d_in, const int* in_sizes, int n_in,
                              void* d_out, int out_size, void* d_ws, size_t ws_size,
                              hipStream_t stream) {
    const float* x  = (const float*)d_in[0];
    const int*   ei = (const int*)d_in[1];   // int32 (JAX x64-disabled)
    const float* W1 = (const float*)d_in[2];
    const float* b1 = (const float*)d_in[3];
    const float* W2 = (const float*)d_in[4];
    const float* b2 = (const float*)d_in[5];
    const float* W3 = (const float*)d_in[6];
    const float* b3 = (const float*)d_in[7];
    float* out = (float*)d_out;

    const int n = out_size;           // 100000
    const int E = in_sizes[1] / 2;    // 1200000
    const int* src = ei;
    const int* dst = ei + E;
    const int ns  = (n + 255) & ~255;
    const int nbk = (n + 255) >> 8;   // 391

    char* w = (char*)d_ws;
    float* dis   = (float*)w;  w += (size_t)ns * 4;
    int*   start = (int*)w;    w += (size_t)(ns + 256) * 4;
    int*   adj   = (int*)w;    w += (size_t)E * 4;
    int*   bcnt  = (int*)w;    w += NBKMAX * 4;
    int*   bbase = (int*)w;    w += (NBKMAX + 1) * 4;
    int*   bcur  = (int*)w;    w += NBKMAX * 4;
    unsigned short* gbuf1 = (unsigned short*)w;  w += (size_t)n * NF * 2;  // 12.8 MB
    unsigned short* gbuf2 = (unsigned short*)w;  w += (size_t)n * NF * 2;  // 12.8 MB
    float* agg   = (float*)w;  // 25.6 MB fp32; pairs (9.6 MB) aliased here (dead before gather1 writes)
    uint2* pairs = (uint2*)agg;

    const int B = 256;

    // CSR build
    k_zero<<<(nbk + B - 1) / B, B, 0, stream>>>(bcnt, nbk);
    k_bhist<<<512, B, 0, stream>>>(dst, bcnt, E, nbk);
    k_bscan<<<1, 512, 0, stream>>>(bcnt, bbase, bcur, start, nbk, n, E);
    k_bscatter<<<(E + CHUNK - 1) / CHUNK, B, 0, stream>>>(src, dst, bcur, pairs, E, nbk);
    k_bsort<<<nbk, B, 0, stream>>>(pairs, bbase, start, adj, dis, n);

    // ----- layer 1 -----
    k_gemm<128><<<(n + 63) / 64, B, 0, stream>>>(x, W1, nullptr, dis, gbuf1, n);
    k_gather<<<(n + 3) / 4, B, 0, stream>>>(gbuf1, adj, start, dis, agg, n);

    // ----- layer 2 + head -----
    k_gemm<64><<<(n + 63) / 64, B, 0, stream>>>(agg, W2, b1, dis, gbuf2, n);
    k_gather_final<<<(n + 3) / 4, B, 0, stream>>>(gbuf2, adj, start, dis, b2, W3, b3, out, n);
}

// Round 6
// 203.448 us; speedup vs baseline: 10.8336x; 1.1188x over previous
//
#include <hip/hip_runtime.h>

#define NF 64
#define NBKMAX 512   // buckets of 256 nodes; n=100K -> 391 buckets
#define CHUNK 4096

// bf16 helpers (RNE)
__device__ __forceinline__ unsigned short f2bf(float f) {
    union { float f; unsigned u; } c; c.f = f;
    unsigned u = c.u;
    return (unsigned short)((u + 0x7FFFu + ((u >> 16) & 1u)) >> 16);
}
__device__ __forceinline__ float bf2f(unsigned short v) {
    union { unsigned u; float f; } c; c.u = ((unsigned)v) << 16;
    return c.f;
}

// ---------------- bucket-radix CSR build ----------------
__global__ void k_zero(int* __restrict__ p, int m) {
    int i = blockIdx.x * blockDim.x + threadIdx.x;
    if (i < m) p[i] = 0;
}

__global__ __launch_bounds__(256) void k_bhist(const int* __restrict__ dst,
                                               int* __restrict__ bcnt, int E, int nbk) {
    __shared__ int h[NBKMAX];
    for (int i = threadIdx.x; i < nbk; i += 256) h[i] = 0;
    __syncthreads();
    int stride = gridDim.x * 256;
    for (int i = blockIdx.x * 256 + threadIdx.x; i < E; i += stride)
        atomicAdd(&h[((unsigned)dst[i]) >> 8], 1);
    __syncthreads();
    for (int i = threadIdx.x; i < nbk; i += 256) {
        int c = h[i];
        if (c) atomicAdd(&bcnt[i], c);
    }
}

__global__ __launch_bounds__(512) void k_bscan(const int* __restrict__ bcnt,
                                               int* __restrict__ bbase, int* __restrict__ bcur,
                                               int* __restrict__ start, int nbk, int n, int E) {
    __shared__ int s[512];
    int t = threadIdx.x;
    int v = (t < nbk) ? bcnt[t] : 0;
    s[t] = v; __syncthreads();
    for (int off = 1; off < 512; off <<= 1) {
        int u = (t >= off) ? s[t - off] : 0;
        __syncthreads();
        s[t] += u;
        __syncthreads();
    }
    int exc = s[t] - v;
    if (t < nbk) { bbase[t] = exc; bcur[t] = exc; }
    if (t == 0) { bbase[nbk] = E; start[n] = E; }
}

__global__ __launch_bounds__(256) void k_bscatter(const int* __restrict__ src,
                                                  const int* __restrict__ dst,
                                                  int* __restrict__ bcur,
                                                  uint2* __restrict__ pairs, int E, int nbk) {
    __shared__ int hist[NBKMAX];
    __shared__ int base[NBKMAX];
    __shared__ uint2 stage[CHUNK];
    int e0 = blockIdx.x * CHUNK;
    int cnt = E - e0; if (cnt > CHUNK) cnt = CHUNK;
    for (int i = threadIdx.x; i < nbk; i += 256) hist[i] = 0;
    __syncthreads();
    for (int i = threadIdx.x; i < cnt; i += 256) {
        int s = src[e0 + i], d = dst[e0 + i];
        stage[i] = make_uint2((unsigned)s, (unsigned)d);
        atomicAdd(&hist[((unsigned)d) >> 8], 1);
    }
    __syncthreads();
    for (int i = threadIdx.x; i < nbk; i += 256) {
        int c = hist[i];
        base[i] = c ? atomicAdd(&bcur[i], c) : 0;
        hist[i] = 0;   // reuse as local cursor
    }
    __syncthreads();
    for (int i = threadIdx.x; i < cnt; i += 256) {
        uint2 p = stage[i];
        int b = p.y >> 8;
        int off = atomicAdd(&hist[b], 1);
        pairs[base[b] + off] = p;
    }
}

__global__ __launch_bounds__(256) void k_bsort(const uint2* __restrict__ pairs,
                                               const int* __restrict__ bbase,
                                               int* __restrict__ start, int* __restrict__ adj,
                                               float* __restrict__ dis, int n) {
    __shared__ int cnt[256];
    __shared__ int cur[256];
    int b  = blockIdx.x;
    int nb = b << 8;
    int nn = n - nb; if (nn > 256) nn = 256;
    int eb = bbase[b];
    int ec = bbase[b + 1] - eb;
    int t  = threadIdx.x;
    cnt[t] = 0;
    __syncthreads();
    for (int i = t; i < ec; i += 256)
        atomicAdd(&cnt[pairs[eb + i].y & 255], 1);
    __syncthreads();
    int v = cnt[t];
    __syncthreads();
    for (int off = 1; off < 256; off <<= 1) {
        int u = (t >= off) ? cnt[t - off] : 0;
        __syncthreads();
        cnt[t] += u;
        __syncthreads();
    }
    int exc = cnt[t] - v;
    if (t < nn) {
        start[nb + t] = eb + exc;
        dis[nb + t]   = rsqrtf((float)(v + 1));
    }
    cur[t] = exc;
    __syncthreads();
    for (int i = t; i < ec; i += 256) {
        uint2 p = pairs[eb + i];
        int off = atomicAdd(&cur[p.y & 255], 1);
        adj[eb + off] = (int)p.x;
    }
}

// ---------------- GEMM: gbf16[n,64] = (act(A[n,K]) @ W[K,64]) * dis[row] ----------------
// K-tiled by 32 (16 KB LDS -> ~5 blocks/CU) with rotation-swizzled sxT
// (bank = (r + 4*rho(k)) mod 32, 2 lanes/bank -> conflict-free writes).
#define KT 32
__device__ __forceinline__ int swz(int kk, int r) {          // rho(k) = (5*(k>>2)+(k&3))&7
    int rho = (5 * (kk >> 2) + (kk & 3)) & 7;
    return kk * 64 + ((r + 4 * rho) & 63);
}

template<int K>
__global__ __launch_bounds__(256) void k_gemm(const float* __restrict__ A,
                                              const float* __restrict__ W,
                                              const float* __restrict__ bias_in,
                                              const float* __restrict__ dis,
                                              unsigned short* __restrict__ out, int n) {
    __shared__ float sW[KT * NF];    // 8 KB
    __shared__ float sxT[KT * 64];   // 8 KB, swizzled [k][r]
    const int tid = threadIdx.x;
    const int row_base = blockIdx.x * 64;
    const int tx = tid & 15, ty = tid >> 4;
    const int c0 = tx * 4, r0 = ty * 4;
    float acc[4][4] = {{0.f}};

    for (int kt = 0; kt < K; kt += KT) {
        __syncthreads();   // previous tile's reads complete
        // stage W tile (linear, conflict-free)
        for (int i = tid * 4; i < KT * NF; i += 256 * 4)
            *(float4*)&sW[i] = *(const float4*)&W[kt * NF + i];
        // stage A tile, transposed + swizzled
        #pragma unroll
        for (int it = 0; it < 2; ++it) {
            int v  = tid + it * 256;
            int r  = v >> 3;          // 0..63
            int kv = v & 7;           // 0..7 (float4 chunk)
            int rg = row_base + r;
            float4 val = make_float4(0.f, 0.f, 0.f, 0.f);
            if (rg < n) val = *(const float4*)&A[(size_t)rg * K + kt + kv * 4];
            if (bias_in) {
                val.x = fmaxf(val.x + bias_in[kt + kv * 4 + 0], 0.f);
                val.y = fmaxf(val.y + bias_in[kt + kv * 4 + 1], 0.f);
                val.z = fmaxf(val.z + bias_in[kt + kv * 4 + 2], 0.f);
                val.w = fmaxf(val.w + bias_in[kt + kv * 4 + 3], 0.f);
            }
            const float vs[4] = {val.x, val.y, val.z, val.w};
            #pragma unroll
            for (int c = 0; c < 4; ++c)
                sxT[swz(kv * 4 + c, r)] = vs[c];
        }
        __syncthreads();

        #pragma unroll
        for (int kk = 0; kk < KT; ++kk) {
            const float4 xv = *(const float4*)&sxT[swz(kk, r0)];   // rho const-folded
            const float4 wv = *(const float4*)&sW[kk * 64 + c0];
            const float xs[4] = {xv.x, xv.y, xv.z, xv.w};
            const float ws[4] = {wv.x, wv.y, wv.z, wv.w};
            #pragma unroll
            for (int i = 0; i < 4; ++i)
                #pragma unroll
                for (int j = 0; j < 4; ++j)
                    acc[i][j] += xs[i] * ws[j];
        }
    }

    #pragma unroll
    for (int i = 0; i < 4; ++i) {
        int r = row_base + r0 + i;
        if (r < n) {
            float sc = dis[r];
            ushort4 o;
            o.x = f2bf(acc[i][0] * sc);
            o.y = f2bf(acc[i][1] * sc);
            o.z = f2bf(acc[i][2] * sc);
            o.w = f2bf(acc[i][3] * sc);
            *(ushort4*)&out[(size_t)r * NF + c0] = o;
        }
    }
}

// ---------------- gather: out[d,:] = dis[d] * (g[d,:] + sum g[adj,:]) ----------------
__global__ __launch_bounds__(256) void k_gather(const unsigned short* __restrict__ g,
                                                const int* __restrict__ adj,
                                                const int* __restrict__ start,
                                                const float* __restrict__ dis,
                                                float* __restrict__ out, int n) {
    int node = blockIdx.x * 4 + (threadIdx.x >> 6);
    int lane = threadIdx.x & 63;
    if (node >= n) return;
    int s = start[node], e = start[node + 1];
    float a0 = bf2f(g[(size_t)node * NF + lane]);
    float a1 = 0.f, a2 = 0.f, a3 = 0.f;
    for (int base = s; base < e; base += 64) {
        int m = e - base; if (m > 64) m = 64;
        int idx = (lane < m) ? adj[base + lane] : 0;
        int j = 0;
        for (; j + 3 < m; j += 4) {
            int u0 = __shfl(idx, j),     u1 = __shfl(idx, j + 1);
            int u2 = __shfl(idx, j + 2), u3 = __shfl(idx, j + 3);
            a0 += bf2f(g[(size_t)u0 * NF + lane]);
            a1 += bf2f(g[(size_t)u1 * NF + lane]);
            a2 += bf2f(g[(size_t)u2 * NF + lane]);
            a3 += bf2f(g[(size_t)u3 * NF + lane]);
        }
        for (; j < m; ++j) {
            int u = __shfl(idx, j);
            a0 += bf2f(g[(size_t)u * NF + lane]);
        }
    }
    out[(size_t)node * NF + lane] = (a0 + a1 + a2 + a3) * dis[node];
}

// ---------------- gather + head fused ----------------
__global__ __launch_bounds__(256) void k_gather_final(const unsigned short* __restrict__ g,
                                                      const int* __restrict__ adj,
                                                      const int* __restrict__ start,
                                                      const float* __restrict__ dis,
                                                      const float* __restrict__ b2,
                                                      const float* __restrict__ W3,
                                                      const float* __restrict__ b3,
                                                      float* __restrict__ out, int n) {
    int node = blockIdx.x * 4 + (threadIdx.x >> 6);
    int lane = threadIdx.x & 63;
    if (node >= n) return;
    int s = start[node], e = start[node + 1];
    float a0 = bf2f(g[(size_t)node * NF + lane]);
    float a1 = 0.f, a2 = 0.f, a3 = 0.f;
    for (int base = s; base < e; base += 64) {
        int m = e - base; if (m > 64) m = 64;
        int idx = (lane < m) ? adj[base + lane] : 0;
        int j = 0;
        for (; j + 3 < m; j += 4) {
            int u0 = __shfl(idx, j),     u1 = __shfl(idx, j + 1);
            int u2 = __shfl(idx, j + 2), u3 = __shfl(idx, j + 3);
            a0 += bf2f(g[(size_t)u0 * NF + lane]);
            a1 += bf2f(g[(size_t)u1 * NF + lane]);
            a2 += bf2f(g[(size_t)u2 * NF + lane]);
            a3 += bf2f(g[(size_t)u3 * NF + lane]);
        }
        for (; j < m; ++j) {
            int u = __shfl(idx, j);
            a0 += bf2f(g[(size_t)u * NF + lane]);
        }
    }
    float val = (a0 + a1 + a2 + a3) * dis[node];
    float v = fmaxf(val + b2[lane], 0.f) * W3[lane];
    #pragma unroll
    for (int off = 32; off > 0; off >>= 1) v += __shfl_down(v, off);
    if (lane == 0) out[node] = v + b3[0];
}

extern "C" void kernel_launch(void* const* d_in, const int* in_sizes, int n_in,
                              void* d_out, int out_size, void* d_ws, size_t ws_size,
                              hipStream_t stream) {
    const float* x  = (const float*)d_in[0];
    const int*   ei = (const int*)d_in[1];   // int32 (JAX x64-disabled)
    const float* W1 = (const float*)d_in[2];
    const float* b1 = (const float*)d_in[3];
    const float* W2 = (const float*)d_in[4];
    const float* b2 = (const float*)d_in[5];
    const float* W3 = (const float*)d_in[6];
    const float* b3 = (const float*)d_in[7];
    float* out = (float*)d_out;

    const int n = out_size;           // 100000
    const int E = in_sizes[1] / 2;    // 1200000
    const int* src = ei;
    const int* dst = ei + E;
    const int ns  = (n + 255) & ~255;
    const int nbk = (n + 255) >> 8;   // 391

    char* w = (char*)d_ws;
    float* dis   = (float*)w;  w += (size_t)ns * 4;
    int*   start = (int*)w;    w += (size_t)(ns + 256) * 4;
    int*   adj   = (int*)w;    w += (size_t)E * 4;
    int*   bcnt  = (int*)w;    w += NBKMAX * 4;
    int*   bbase = (int*)w;    w += (NBKMAX + 1) * 4;
    int*   bcur  = (int*)w;    w += NBKMAX * 4;
    unsigned short* gbuf1 = (unsigned short*)w;  w += (size_t)n * NF * 2;  // 12.8 MB
    unsigned short* gbuf2 = (unsigned short*)w;  w += (size_t)n * NF * 2;  // 12.8 MB
    float* agg   = (float*)w;  // 25.6 MB fp32; pairs (9.6 MB) aliased here (dead before gather1 writes)
    uint2* pairs = (uint2*)agg;

    const int B = 256;

    // CSR build
    k_zero<<<(nbk + B - 1) / B, B, 0, stream>>>(bcnt, nbk);
    k_bhist<<<512, B, 0, stream>>>(dst, bcnt, E, nbk);
    k_bscan<<<1, 512, 0, stream>>>(bcnt, bbase, bcur, start, nbk, n, E);
    k_bscatter<<<(E + CHUNK - 1) / CHUNK, B, 0, stream>>>(src, dst, bcur, pairs, E, nbk);
    k_bsort<<<nbk, B, 0, stream>>>(pairs, bbase, start, adj, dis, n);

    // ----- layer 1 -----
    k_gemm<128><<<(n + 63) / 64, B, 0, stream>>>(x, W1, nullptr, dis, gbuf1, n);
    k_gather<<<(n + 3) / 4, B, 0, stream>>>(gbuf1, adj, start, dis, agg, n);

    // ----- layer 2 + head -----
    k_gemm<64><<<(n + 63) / 64, B, 0, stream>>>(agg, W2, b1, dis, gbuf2, n);
    k_gather_final<<<(n + 3) / 4, B, 0, stream>>>(gbuf2, adj, start, dis, b2, W3, b3, out, n);
}

// Round 7
// 199.446 us; speedup vs baseline: 11.0510x; 1.0201x over previous
//
#include <hip/hip_runtime.h>

#define NF 64
#define NBKMAX 512   // buckets of 256 nodes; n=100K -> 391 buckets
#define CHUNK 4096

// bf16 helpers (RNE)
__device__ __forceinline__ unsigned short f2bf(float f) {
    union { float f; unsigned u; } c; c.f = f;
    unsigned u = c.u;
    return (unsigned short)((u + 0x7FFFu + ((u >> 16) & 1u)) >> 16);
}
// packed pair of bf16 -> (lo, hi) floats
__device__ __forceinline__ float2 bfp2(unsigned v) {
    union { unsigned u; float f; } lo, hi;
    lo.u = v << 16;
    hi.u = v & 0xffff0000u;
    return make_float2(lo.f, hi.f);
}

// ---------------- bucket-radix CSR build ----------------
__global__ void k_zero(int* __restrict__ p, int m) {
    int i = blockIdx.x * blockDim.x + threadIdx.x;
    if (i < m) p[i] = 0;
}

__global__ __launch_bounds__(256) void k_bhist(const int* __restrict__ dst,
                                               int* __restrict__ bcnt, int E, int nbk) {
    __shared__ int h[NBKMAX];
    for (int i = threadIdx.x; i < nbk; i += 256) h[i] = 0;
    __syncthreads();
    int stride = gridDim.x * 256;
    for (int i = blockIdx.x * 256 + threadIdx.x; i < E; i += stride)
        atomicAdd(&h[((unsigned)dst[i]) >> 8], 1);
    __syncthreads();
    for (int i = threadIdx.x; i < nbk; i += 256) {
        int c = h[i];
        if (c) atomicAdd(&bcnt[i], c);
    }
}

__global__ __launch_bounds__(512) void k_bscan(const int* __restrict__ bcnt,
                                               int* __restrict__ bbase, int* __restrict__ bcur,
                                               int* __restrict__ start, int nbk, int n, int E) {
    __shared__ int s[512];
    int t = threadIdx.x;
    int v = (t < nbk) ? bcnt[t] : 0;
    s[t] = v; __syncthreads();
    for (int off = 1; off < 512; off <<= 1) {
        int u = (t >= off) ? s[t - off] : 0;
        __syncthreads();
        s[t] += u;
        __syncthreads();
    }
    int exc = s[t] - v;
    if (t < nbk) { bbase[t] = exc; bcur[t] = exc; }
    if (t == 0) { bbase[nbk] = E; start[n] = E; }
}

__global__ __launch_bounds__(256) void k_bscatter(const int* __restrict__ src,
                                                  const int* __restrict__ dst,
                                                  int* __restrict__ bcur,
                                                  uint2* __restrict__ pairs, int E, int nbk) {
    __shared__ int hist[NBKMAX];
    __shared__ int base[NBKMAX];
    __shared__ uint2 stage[CHUNK];
    int e0 = blockIdx.x * CHUNK;
    int cnt = E - e0; if (cnt > CHUNK) cnt = CHUNK;
    for (int i = threadIdx.x; i < nbk; i += 256) hist[i] = 0;
    __syncthreads();
    for (int i = threadIdx.x; i < cnt; i += 256) {
        int s = src[e0 + i], d = dst[e0 + i];
        stage[i] = make_uint2((unsigned)s, (unsigned)d);
        atomicAdd(&hist[((unsigned)d) >> 8], 1);
    }
    __syncthreads();
    for (int i = threadIdx.x; i < nbk; i += 256) {
        int c = hist[i];
        base[i] = c ? atomicAdd(&bcur[i], c) : 0;
        hist[i] = 0;   // reuse as local cursor
    }
    __syncthreads();
    for (int i = threadIdx.x; i < cnt; i += 256) {
        uint2 p = stage[i];
        int b = p.y >> 8;
        int off = atomicAdd(&hist[b], 1);
        pairs[base[b] + off] = p;
    }
}

__global__ __launch_bounds__(256) void k_bsort(const uint2* __restrict__ pairs,
                                               const int* __restrict__ bbase,
                                               int* __restrict__ start, int* __restrict__ adj,
                                               float* __restrict__ dis, int n) {
    __shared__ int cnt[256];
    __shared__ int cur[256];
    int b  = blockIdx.x;
    int nb = b << 8;
    int nn = n - nb; if (nn > 256) nn = 256;
    int eb = bbase[b];
    int ec = bbase[b + 1] - eb;
    int t  = threadIdx.x;
    cnt[t] = 0;
    __syncthreads();
    for (int i = t; i < ec; i += 256)
        atomicAdd(&cnt[pairs[eb + i].y & 255], 1);
    __syncthreads();
    int v = cnt[t];
    __syncthreads();
    for (int off = 1; off < 256; off <<= 1) {
        int u = (t >= off) ? cnt[t - off] : 0;
        __syncthreads();
        cnt[t] += u;
        __syncthreads();
    }
    int exc = cnt[t] - v;
    if (t < nn) {
        start[nb + t] = eb + exc;
        dis[nb + t]   = rsqrtf((float)(v + 1));
    }
    cur[t] = exc;
    __syncthreads();
    for (int i = t; i < ec; i += 256) {
        uint2 p = pairs[eb + i];
        int off = atomicAdd(&cur[p.y & 255], 1);
        adj[eb + off] = (int)p.x;
    }
}

// ---------------- GEMM: gbf16[n,64] = (act(A[n,K]) @ W[K,64]) * dis[row] ----------------
#define KT 32
__device__ __forceinline__ int swz(int kk, int r) {          // rho(k) = (5*(k>>2)+(k&3))&7
    int rho = (5 * (kk >> 2) + (kk & 3)) & 7;
    return kk * 64 + ((r + 4 * rho) & 63);
}

template<int K>
__global__ __launch_bounds__(256) void k_gemm(const float* __restrict__ A,
                                              const float* __restrict__ W,
                                              const float* __restrict__ bias_in,
                                              const float* __restrict__ dis,
                                              unsigned short* __restrict__ out, int n) {
    __shared__ float sW[KT * NF];    // 8 KB
    __shared__ float sxT[KT * 64];   // 8 KB, swizzled [k][r]
    const int tid = threadIdx.x;
    const int row_base = blockIdx.x * 64;
    const int tx = tid & 15, ty = tid >> 4;
    const int c0 = tx * 4, r0 = ty * 4;
    float acc[4][4] = {{0.f}};

    for (int kt = 0; kt < K; kt += KT) {
        __syncthreads();
        for (int i = tid * 4; i < KT * NF; i += 256 * 4)
            *(float4*)&sW[i] = *(const float4*)&W[kt * NF + i];
        #pragma unroll
        for (int it = 0; it < 2; ++it) {
            int v  = tid + it * 256;
            int r  = v >> 3;
            int kv = v & 7;
            int rg = row_base + r;
            float4 val = make_float4(0.f, 0.f, 0.f, 0.f);
            if (rg < n) val = *(const float4*)&A[(size_t)rg * K + kt + kv * 4];
            if (bias_in) {
                val.x = fmaxf(val.x + bias_in[kt + kv * 4 + 0], 0.f);
                val.y = fmaxf(val.y + bias_in[kt + kv * 4 + 1], 0.f);
                val.z = fmaxf(val.z + bias_in[kt + kv * 4 + 2], 0.f);
                val.w = fmaxf(val.w + bias_in[kt + kv * 4 + 3], 0.f);
            }
            const float vs[4] = {val.x, val.y, val.z, val.w};
            #pragma unroll
            for (int c = 0; c < 4; ++c)
                sxT[swz(kv * 4 + c, r)] = vs[c];
        }
        __syncthreads();

        #pragma unroll
        for (int kk = 0; kk < KT; ++kk) {
            const float4 xv = *(const float4*)&sxT[swz(kk, r0)];
            const float4 wv = *(const float4*)&sW[kk * 64 + c0];
            const float xs[4] = {xv.x, xv.y, xv.z, xv.w};
            const float ws[4] = {wv.x, wv.y, wv.z, wv.w};
            #pragma unroll
            for (int i = 0; i < 4; ++i)
                #pragma unroll
                for (int j = 0; j < 4; ++j)
                    acc[i][j] += xs[i] * ws[j];
        }
    }

    #pragma unroll
    for (int i = 0; i < 4; ++i) {
        int r = row_base + r0 + i;
        if (r < n) {
            float sc = dis[r];
            ushort4 o;
            o.x = f2bf(acc[i][0] * sc);
            o.y = f2bf(acc[i][1] * sc);
            o.z = f2bf(acc[i][2] * sc);
            o.w = f2bf(acc[i][3] * sc);
            *(ushort4*)&out[(size_t)r * NF + c0] = o;
        }
    }
}

// ---------------- gather v2: lane = packed feature pair; wave halves = different edges --------
// Each lane loads a uint (2 bf16). Lanes 0-31 / 32-63 process disjoint edge subsets
// (half h takes edges j+4h..j+4h+3 in the unrolled loop; stride-2 split in the tail).
// 8 edge-rows in flight per wave. Halves merged with one shfl_xor(32) at the end.
__global__ __launch_bounds__(256) void k_gather(const unsigned short* __restrict__ g,
                                                const int* __restrict__ adj,
                                                const int* __restrict__ start,
                                                const float* __restrict__ dis,
                                                float* __restrict__ out, int n) {
    int node = blockIdx.x * 4 + (threadIdx.x >> 6);
    int lane = threadIdx.x & 63;
    if (node >= n) return;
    int half = lane >> 5, sl = lane & 31;
    int s = start[node], e = start[node + 1];
    float2 a0 = {0.f, 0.f}, a1 = {0.f, 0.f}, a2 = {0.f, 0.f}, a3 = {0.f, 0.f};
    if (half == 0) {   // self-loop term, counted once
        float2 p = bfp2(*(const unsigned*)&g[(size_t)node * NF + sl * 2]);
        a0.x += p.x; a0.y += p.y;
    }
    for (int base = s; base < e; base += 64) {
        int m = e - base; if (m > 64) m = 64;
        int idx = (lane < m) ? adj[base + lane] : 0;
        int j = 0;
        for (; j + 8 <= m; j += 8) {
            int j0 = j + half * 4;
            int u0 = __shfl(idx, j0),     u1 = __shfl(idx, j0 + 1);
            int u2 = __shfl(idx, j0 + 2), u3 = __shfl(idx, j0 + 3);
            unsigned v0 = *(const unsigned*)&g[(size_t)u0 * NF + sl * 2];
            unsigned v1 = *(const unsigned*)&g[(size_t)u1 * NF + sl * 2];
            unsigned v2 = *(const unsigned*)&g[(size_t)u2 * NF + sl * 2];
            unsigned v3 = *(const unsigned*)&g[(size_t)u3 * NF + sl * 2];
            float2 p0 = bfp2(v0), p1 = bfp2(v1), p2 = bfp2(v2), p3 = bfp2(v3);
            a0.x += p0.x; a0.y += p0.y;
            a1.x += p1.x; a1.y += p1.y;
            a2.x += p2.x; a2.y += p2.y;
            a3.x += p3.x; a3.y += p3.y;
        }
        for (; j < m; j += 2) {
            int jj = j + half;
            if (jj < m) {
                int u = __shfl(idx, jj);
                float2 p = bfp2(*(const unsigned*)&g[(size_t)u * NF + sl * 2]);
                a0.x += p.x; a0.y += p.y;
            }
        }
    }
    float2 t;
    t.x = a0.x + a1.x + a2.x + a3.x;
    t.y = a0.y + a1.y + a2.y + a3.y;
    t.x += __shfl_xor(t.x, 32);
    t.y += __shfl_xor(t.y, 32);
    if (half == 0) {
        float sc = dis[node];
        *(float2*)&out[(size_t)node * NF + sl * 2] = make_float2(t.x * sc, t.y * sc);
    }
}

// ---------------- gather v2 + head fused ----------------
__global__ __launch_bounds__(256) void k_gather_final(const unsigned short* __restrict__ g,
                                                      const int* __restrict__ adj,
                                                      const int* __restrict__ start,
                                                      const float* __restrict__ dis,
                                                      const float* __restrict__ b2,
                                                      const float* __restrict__ W3,
                                                      const float* __restrict__ b3,
                                                      float* __restrict__ out, int n) {
    int node = blockIdx.x * 4 + (threadIdx.x >> 6);
    int lane = threadIdx.x & 63;
    if (node >= n) return;
    int half = lane >> 5, sl = lane & 31;
    int s = start[node], e = start[node + 1];
    float2 a0 = {0.f, 0.f}, a1 = {0.f, 0.f}, a2 = {0.f, 0.f}, a3 = {0.f, 0.f};
    if (half == 0) {
        float2 p = bfp2(*(const unsigned*)&g[(size_t)node * NF + sl * 2]);
        a0.x += p.x; a0.y += p.y;
    }
    for (int base = s; base < e; base += 64) {
        int m = e - base; if (m > 64) m = 64;
        int idx = (lane < m) ? adj[base + lane] : 0;
        int j = 0;
        for (; j + 8 <= m; j += 8) {
            int j0 = j + half * 4;
            int u0 = __shfl(idx, j0),     u1 = __shfl(idx, j0 + 1);
            int u2 = __shfl(idx, j0 + 2), u3 = __shfl(idx, j0 + 3);
            unsigned v0 = *(const unsigned*)&g[(size_t)u0 * NF + sl * 2];
            unsigned v1 = *(const unsigned*)&g[(size_t)u1 * NF + sl * 2];
            unsigned v2 = *(const unsigned*)&g[(size_t)u2 * NF + sl * 2];
            unsigned v3 = *(const unsigned*)&g[(size_t)u3 * NF + sl * 2];
            float2 p0 = bfp2(v0), p1 = bfp2(v1), p2 = bfp2(v2), p3 = bfp2(v3);
            a0.x += p0.x; a0.y += p0.y;
            a1.x += p1.x; a1.y += p1.y;
            a2.x += p2.x; a2.y += p2.y;
            a3.x += p3.x; a3.y += p3.y;
        }
        for (; j < m; j += 2) {
            int jj = j + half;
            if (jj < m) {
                int u = __shfl(idx, jj);
                float2 p = bfp2(*(const unsigned*)&g[(size_t)u * NF + sl * 2]);
                a0.x += p.x; a0.y += p.y;
            }
        }
    }
    float2 t;
    t.x = a0.x + a1.x + a2.x + a3.x;
    t.y = a0.y + a1.y + a2.y + a3.y;
    t.x += __shfl_xor(t.x, 32);
    t.y += __shfl_xor(t.y, 32);
    float sc = dis[node];
    float f0 = sl * 2, dummy;
    (void)f0; (void)dummy;
    float v = fmaxf(t.x * sc + b2[sl * 2], 0.f)     * W3[sl * 2]
            + fmaxf(t.y * sc + b2[sl * 2 + 1], 0.f) * W3[sl * 2 + 1];
    #pragma unroll
    for (int off = 16; off > 0; off >>= 1) v += __shfl_down(v, off, 32);
    if (lane == 0) out[node] = v + b3[0];
}

extern "C" void kernel_launch(void* const* d_in, const int* in_sizes, int n_in,
                              void* d_out, int out_size, void* d_ws, size_t ws_size,
                              hipStream_t stream) {
    const float* x  = (const float*)d_in[0];
    const int*   ei = (const int*)d_in[1];   // int32 (JAX x64-disabled)
    const float* W1 = (const float*)d_in[2];
    const float* b1 = (const float*)d_in[3];
    const float* W2 = (const float*)d_in[4];
    const float* b2 = (const float*)d_in[5];
    const float* W3 = (const float*)d_in[6];
    const float* b3 = (const float*)d_in[7];
    float* out = (float*)d_out;

    const int n = out_size;           // 100000
    const int E = in_sizes[1] / 2;    // 1200000
    const int* src = ei;
    const int* dst = ei + E;
    const int ns  = (n + 255) & ~255;
    const int nbk = (n + 255) >> 8;   // 391

    char* w = (char*)d_ws;
    float* dis   = (float*)w;  w += (size_t)ns * 4;
    int*   start = (int*)w;    w += (size_t)(ns + 256) * 4;
    int*   adj   = (int*)w;    w += (size_t)E * 4;
    int*   bcnt  = (int*)w;    w += NBKMAX * 4;
    int*   bbase = (int*)w;    w += (NBKMAX + 1) * 4;
    int*   bcur  = (int*)w;    w += NBKMAX * 4;
    unsigned short* gbuf1 = (unsigned short*)w;  w += (size_t)n * NF * 2;
    unsigned short* gbuf2 = (unsigned short*)w;  w += (size_t)n * NF * 2;
    float* agg   = (float*)w;  // fp32; pairs (9.6 MB) aliased here (dead before gather1 writes)
    uint2* pairs = (uint2*)agg;

    const int B = 256;

    // CSR build
    k_zero<<<(nbk + B - 1) / B, B, 0, stream>>>(bcnt, nbk);
    k_bhist<<<512, B, 0, stream>>>(dst, bcnt, E, nbk);
    k_bscan<<<1, 512, 0, stream>>>(bcnt, bbase, bcur, start, nbk, n, E);
    k_bscatter<<<(E + CHUNK - 1) / CHUNK, B, 0, stream>>>(src, dst, bcur, pairs, E, nbk);
    k_bsort<<<nbk, B, 0, stream>>>(pairs, bbase, start, adj, dis, n);

    // ----- layer 1 -----
    k_gemm<128><<<(n + 63) / 64, B, 0, stream>>>(x, W1, nullptr, dis, gbuf1, n);
    k_gather<<<(n + 3) / 4, B, 0, stream>>>(gbuf1, adj, start, dis, agg, n);

    // ----- layer 2 + head -----
    k_gemm<64><<<(n + 63) / 64, B, 0, stream>>>(agg, W2, b1, dis, gbuf2, n);
    k_gather_final<<<(n + 3) / 4, B, 0, stream>>>(gbuf2, adj, start, dis, b2, W3, b3, out, n);
}

// Round 9
// 193.731 us; speedup vs baseline: 11.3770x; 1.0295x over previous
//
#include <hip/hip_runtime.h>

#define NF 64
#define NBKMAX 512   // buckets of 256 nodes; n=100K -> 391 buckets
#define CHUNK 4096

// bf16 helpers (RNE)
__device__ __forceinline__ unsigned short f2bf(float f) {
    union { float f; unsigned u; } c; c.f = f;
    unsigned u = c.u;
    return (unsigned short)((u + 0x7FFFu + ((u >> 16) & 1u)) >> 16);
}
// packed pair of bf16 -> (lo, hi) floats
__device__ __forceinline__ float2 bfp2(unsigned v) {
    union { unsigned u; float f; } lo, hi;
    lo.u = v << 16;
    hi.u = v & 0xffff0000u;
    return make_float2(lo.f, hi.f);
}

// ---------------- bucket-radix CSR build ----------------
__global__ void k_zero(int* __restrict__ p, int m) {
    int i = blockIdx.x * blockDim.x + threadIdx.x;
    if (i < m) p[i] = 0;
}

__global__ __launch_bounds__(256) void k_bhist(const int* __restrict__ dst,
                                               int* __restrict__ bcnt, int E, int nbk) {
    __shared__ int h[NBKMAX];
    for (int i = threadIdx.x; i < nbk; i += 256) h[i] = 0;
    __syncthreads();
    int stride = gridDim.x * 256;
    for (int i = blockIdx.x * 256 + threadIdx.x; i < E; i += stride)
        atomicAdd(&h[((unsigned)dst[i]) >> 8], 1);
    __syncthreads();
    for (int i = threadIdx.x; i < nbk; i += 256) {
        int c = h[i];
        if (c) atomicAdd(&bcnt[i], c);
    }
}

__global__ __launch_bounds__(512) void k_bscan(const int* __restrict__ bcnt,
                                               int* __restrict__ bbase, int* __restrict__ bcur,
                                               int* __restrict__ start, int nbk, int n, int E) {
    __shared__ int s[512];
    int t = threadIdx.x;
    int v = (t < nbk) ? bcnt[t] : 0;
    s[t] = v; __syncthreads();
    for (int off = 1; off < 512; off <<= 1) {
        int u = (t >= off) ? s[t - off] : 0;
        __syncthreads();
        s[t] += u;
        __syncthreads();
    }
    int exc = s[t] - v;
    if (t < nbk) { bbase[t] = exc; bcur[t] = exc; }
    if (t == 0) { bbase[nbk] = E; start[n] = E; }
}

__global__ __launch_bounds__(256) void k_bscatter(const int* __restrict__ src,
                                                  const int* __restrict__ dst,
                                                  int* __restrict__ bcur,
                                                  uint2* __restrict__ pairs, int E, int nbk) {
    __shared__ int hist[NBKMAX];
    __shared__ int base[NBKMAX];
    __shared__ uint2 stage[CHUNK];
    int e0 = blockIdx.x * CHUNK;
    int cnt = E - e0; if (cnt > CHUNK) cnt = CHUNK;
    for (int i = threadIdx.x; i < nbk; i += 256) hist[i] = 0;
    __syncthreads();
    for (int i = threadIdx.x; i < cnt; i += 256) {
        int s = src[e0 + i], d = dst[e0 + i];
        stage[i] = make_uint2((unsigned)s, (unsigned)d);
        atomicAdd(&hist[((unsigned)d) >> 8], 1);
    }
    __syncthreads();
    for (int i = threadIdx.x; i < nbk; i += 256) {
        int c = hist[i];
        base[i] = c ? atomicAdd(&bcur[i], c) : 0;
        hist[i] = 0;   // reuse as local cursor
    }
    __syncthreads();
    for (int i = threadIdx.x; i < cnt; i += 256) {
        uint2 p = stage[i];
        int b = p.y >> 8;
        int off = atomicAdd(&hist[b], 1);
        pairs[base[b] + off] = p;
    }
}

__global__ __launch_bounds__(256) void k_bsort(const uint2* __restrict__ pairs,
                                               const int* __restrict__ bbase,
                                               int* __restrict__ start, int* __restrict__ adj,
                                               float* __restrict__ dis, int n) {
    __shared__ int cnt[256];
    __shared__ int cur[256];
    int b  = blockIdx.x;
    int nb = b << 8;
    int nn = n - nb; if (nn > 256) nn = 256;
    int eb = bbase[b];
    int ec = bbase[b + 1] - eb;
    int t  = threadIdx.x;
    cnt[t] = 0;
    __syncthreads();
    for (int i = t; i < ec; i += 256)
        atomicAdd(&cnt[pairs[eb + i].y & 255], 1);
    __syncthreads();
    int v = cnt[t];
    __syncthreads();
    for (int off = 1; off < 256; off <<= 1) {
        int u = (t >= off) ? cnt[t - off] : 0;
        __syncthreads();
        cnt[t] += u;
        __syncthreads();
    }
    int exc = cnt[t] - v;
    if (t < nn) {
        start[nb + t] = eb + exc;
        dis[nb + t]   = rsqrtf((float)(v + 1));
    }
    cur[t] = exc;
    __syncthreads();
    for (int i = t; i < ec; i += 256) {
        uint2 p = pairs[eb + i];
        int off = atomicAdd(&cur[p.y & 255], 1);
        adj[eb + off] = (int)p.x;
    }
}

// ---------------- GEMM: gbf16[n,64] = (act(A[n,K]) @ W[K,64]) * dis[row] ----------------
#define KT 32
__device__ __forceinline__ int swz(int kk, int r) {          // rho(k) = (5*(k>>2)+(k&3))&7
    int rho = (5 * (kk >> 2) + (kk & 3)) & 7;
    return kk * 64 + ((r + 4 * rho) & 63);
}

template<int K>
__global__ __launch_bounds__(256) void k_gemm(const float* __restrict__ A,
                                              const float* __restrict__ W,
                                              const float* __restrict__ bias_in,
                                              const float* __restrict__ dis,
                                              unsigned short* __restrict__ out, int n) {
    __shared__ float sW[KT * NF];    // 8 KB
    __shared__ float sxT[KT * 64];   // 8 KB, swizzled [k][r]
    const int tid = threadIdx.x;
    const int row_base = blockIdx.x * 64;
    const int tx = tid & 15, ty = tid >> 4;
    const int c0 = tx * 4, r0 = ty * 4;
    float acc[4][4] = {{0.f}};

    for (int kt = 0; kt < K; kt += KT) {
        __syncthreads();
        for (int i = tid * 4; i < KT * NF; i += 256 * 4)
            *(float4*)&sW[i] = *(const float4*)&W[kt * NF + i];
        #pragma unroll
        for (int it = 0; it < 2; ++it) {
            int v  = tid + it * 256;
            int r  = v >> 3;
            int kv = v & 7;
            int rg = row_base + r;
            float4 val = make_float4(0.f, 0.f, 0.f, 0.f);
            if (rg < n) val = *(const float4*)&A[(size_t)rg * K + kt + kv * 4];
            if (bias_in) {
                val.x = fmaxf(val.x + bias_in[kt + kv * 4 + 0], 0.f);
                val.y = fmaxf(val.y + bias_in[kt + kv * 4 + 1], 0.f);
                val.z = fmaxf(val.z + bias_in[kt + kv * 4 + 2], 0.f);
                val.w = fmaxf(val.w + bias_in[kt + kv * 4 + 3], 0.f);
            }
            const float vs[4] = {val.x, val.y, val.z, val.w};
            #pragma unroll
            for (int c = 0; c < 4; ++c)
                sxT[swz(kv * 4 + c, r)] = vs[c];
        }
        __syncthreads();

        #pragma unroll
        for (int kk = 0; kk < KT; ++kk) {
            const float4 xv = *(const float4*)&sxT[swz(kk, r0)];
            const float4 wv = *(const float4*)&sW[kk * 64 + c0];
            const float xs[4] = {xv.x, xv.y, xv.z, xv.w};
            const float ws[4] = {wv.x, wv.y, wv.z, wv.w};
            #pragma unroll
            for (int i = 0; i < 4; ++i)
                #pragma unroll
                for (int j = 0; j < 4; ++j)
                    acc[i][j] += xs[i] * ws[j];
        }
    }

    #pragma unroll
    for (int i = 0; i < 4; ++i) {
        int r = row_base + r0 + i;
        if (r < n) {
            float sc = dis[r];
            ushort4 o;
            o.x = f2bf(acc[i][0] * sc);
            o.y = f2bf(acc[i][1] * sc);
            o.z = f2bf(acc[i][2] * sc);
            o.w = f2bf(acc[i][3] * sc);
            *(ushort4*)&out[(size_t)r * NF + c0] = o;
        }
    }
}

// ---------------- gather v3b: lane = 4 features (dwordx2); 4 edge-rows per load instr ---------
// 16 lanes cover one row. Group g16 = lane>>4 takes edge j+g16 (+4).
// FIX vs v3: tail shfl executed UNCONDITIONALLY with clamped source (all 64 lanes active ->
// every source lane active -> ds_bpermute defined); only the load/accumulate is guarded.
__global__ __launch_bounds__(256) void k_gather(const unsigned short* __restrict__ g,
                                                const int* __restrict__ adj,
                                                const int* __restrict__ start,
                                                const float* __restrict__ dis,
                                                float* __restrict__ out, int n) {
    int node = blockIdx.x * 4 + (threadIdx.x >> 6);
    int lane = threadIdx.x & 63;
    if (node >= n) return;
    int g16 = lane >> 4, fl = lane & 15;
    int s = start[node], e = start[node + 1];
    float4 acc0 = {0.f, 0.f, 0.f, 0.f}, acc1 = {0.f, 0.f, 0.f, 0.f};
    if (g16 == 0) {   // self-loop, counted once
        uint2 v = *(const uint2*)&g[(size_t)node * NF + fl * 4];
        float2 pa = bfp2(v.x), pb = bfp2(v.y);
        acc0.x += pa.x; acc0.y += pa.y; acc0.z += pb.x; acc0.w += pb.y;
    }
    for (int base = s; base < e; base += 64) {
        int m = e - base; if (m > 64) m = 64;
        int idx = (lane < m) ? adj[base + lane] : 0;
        int j = 0;
        for (; j + 8 <= m; j += 8) {
            int e0 = __shfl(idx, j + g16);
            int e1 = __shfl(idx, j + 4 + g16);
            uint2 v0 = *(const uint2*)&g[(size_t)e0 * NF + fl * 4];
            uint2 v1 = *(const uint2*)&g[(size_t)e1 * NF + fl * 4];
            float2 p00 = bfp2(v0.x), p01 = bfp2(v0.y);
            float2 p10 = bfp2(v1.x), p11 = bfp2(v1.y);
            acc0.x += p00.x; acc0.y += p00.y; acc0.z += p01.x; acc0.w += p01.y;
            acc1.x += p10.x; acc1.y += p10.y; acc1.z += p11.x; acc1.w += p11.y;
        }
        for (; j < m; j += 4) {
            int jj = j + g16;
            int srcl = jj < m ? jj : (m - 1);   // clamp; shfl runs with ALL lanes active
            int e0 = __shfl(idx, srcl);
            if (jj < m) {
                uint2 v0 = *(const uint2*)&g[(size_t)e0 * NF + fl * 4];
                float2 p00 = bfp2(v0.x), p01 = bfp2(v0.y);
                acc0.x += p00.x; acc0.y += p00.y; acc0.z += p01.x; acc0.w += p01.y;
            }
        }
    }
    float4 t;
    t.x = acc0.x + acc1.x; t.y = acc0.y + acc1.y;
    t.z = acc0.z + acc1.z; t.w = acc0.w + acc1.w;
    t.x += __shfl_xor(t.x, 16); t.y += __shfl_xor(t.y, 16);
    t.z += __shfl_xor(t.z, 16); t.w += __shfl_xor(t.w, 16);
    t.x += __shfl_xor(t.x, 32); t.y += __shfl_xor(t.y, 32);
    t.z += __shfl_xor(t.z, 32); t.w += __shfl_xor(t.w, 32);
    if (g16 == 0) {
        float sc = dis[node];
        *(float4*)&out[(size_t)node * NF + fl * 4] =
            make_float4(t.x * sc, t.y * sc, t.z * sc, t.w * sc);
    }
}

// ---------------- gather v3b + head fused ----------------
__global__ __launch_bounds__(256) void k_gather_final(const unsigned short* __restrict__ g,
                                                      const int* __restrict__ adj,
                                                      const int* __restrict__ start,
                                                      const float* __restrict__ dis,
                                                      const float* __restrict__ b2,
                                                      const float* __restrict__ W3,
                                                      const float* __restrict__ b3,
                                                      float* __restrict__ out, int n) {
    int node = blockIdx.x * 4 + (threadIdx.x >> 6);
    int lane = threadIdx.x & 63;
    if (node >= n) return;
    int g16 = lane >> 4, fl = lane & 15;
    int s = start[node], e = start[node + 1];
    float4 acc0 = {0.f, 0.f, 0.f, 0.f}, acc1 = {0.f, 0.f, 0.f, 0.f};
    if (g16 == 0) {
        uint2 v = *(const uint2*)&g[(size_t)node * NF + fl * 4];
        float2 pa = bfp2(v.x), pb = bfp2(v.y);
        acc0.x += pa.x; acc0.y += pa.y; acc0.z += pb.x; acc0.w += pb.y;
    }
    for (int base = s; base < e; base += 64) {
        int m = e - base; if (m > 64) m = 64;
        int idx = (lane < m) ? adj[base + lane] : 0;
        int j = 0;
        for (; j + 8 <= m; j += 8) {
            int e0 = __shfl(idx, j + g16);
            int e1 = __shfl(idx, j + 4 + g16);
            uint2 v0 = *(const uint2*)&g[(size_t)e0 * NF + fl * 4];
            uint2 v1 = *(const uint2*)&g[(size_t)e1 * NF + fl * 4];
            float2 p00 = bfp2(v0.x), p01 = bfp2(v0.y);
            float2 p10 = bfp2(v1.x), p11 = bfp2(v1.y);
            acc0.x += p00.x; acc0.y += p00.y; acc0.z += p01.x; acc0.w += p01.y;
            acc1.x += p10.x; acc1.y += p10.y; acc1.z += p11.x; acc1.w += p11.y;
        }
        for (; j < m; j += 4) {
            int jj = j + g16;
            int srcl = jj < m ? jj : (m - 1);   // clamp; shfl runs with ALL lanes active
            int e0 = __shfl(idx, srcl);
            if (jj < m) {
                uint2 v0 = *(const uint2*)&g[(size_t)e0 * NF + fl * 4];
                float2 p00 = bfp2(v0.x), p01 = bfp2(v0.y);
                acc0.x += p00.x; acc0.y += p00.y; acc0.z += p01.x; acc0.w += p01.y;
            }
        }
    }
    float4 t;
    t.x = acc0.x + acc1.x; t.y = acc0.y + acc1.y;
    t.z = acc0.z + acc1.z; t.w = acc0.w + acc1.w;
    t.x += __shfl_xor(t.x, 16); t.y += __shfl_xor(t.y, 16);
    t.z += __shfl_xor(t.z, 16); t.w += __shfl_xor(t.w, 16);
    t.x += __shfl_xor(t.x, 32); t.y += __shfl_xor(t.y, 32);
    t.z += __shfl_xor(t.z, 32); t.w += __shfl_xor(t.w, 32);

    float sc = dis[node];
    const float4 bb = *(const float4*)&b2[fl * 4];
    const float4 ww = *(const float4*)&W3[fl * 4];
    float v = fmaxf(t.x * sc + bb.x, 0.f) * ww.x
            + fmaxf(t.y * sc + bb.y, 0.f) * ww.y
            + fmaxf(t.z * sc + bb.z, 0.f) * ww.z
            + fmaxf(t.w * sc + bb.w, 0.f) * ww.w;
    #pragma unroll
    for (int off = 8; off > 0; off >>= 1) v += __shfl_down(v, off, 16);
    if (lane == 0) out[node] = v + b3[0];
}

extern "C" void kernel_launch(void* const* d_in, const int* in_sizes, int n_in,
                              void* d_out, int out_size, void* d_ws, size_t ws_size,
                              hipStream_t stream) {
    const float* x  = (const float*)d_in[0];
    const int*   ei = (const int*)d_in[1];   // int32 (JAX x64-disabled)
    const float* W1 = (const float*)d_in[2];
    const float* b1 = (const float*)d_in[3];
    const float* W2 = (const float*)d_in[4];
    const float* b2 = (const float*)d_in[5];
    const float* W3 = (const float*)d_in[6];
    const float* b3 = (const float*)d_in[7];
    float* out = (float*)d_out;

    const int n = out_size;           // 100000
    const int E = in_sizes[1] / 2;    // 1200000
    const int* src = ei;
    const int* dst = ei + E;
    const int ns  = (n + 255) & ~255;
    const int nbk = (n + 255) >> 8;   // 391

    char* w = (char*)d_ws;
    float* dis   = (float*)w;  w += (size_t)ns * 4;
    int*   start = (int*)w;    w += (size_t)(ns + 256) * 4;
    int*   adj   = (int*)w;    w += (size_t)E * 4;
    int*   bcnt  = (int*)w;    w += NBKMAX * 4;
    int*   bbase = (int*)w;    w += (NBKMAX + 1) * 4;
    int*   bcur  = (int*)w;    w += NBKMAX * 4;
    unsigned short* gbuf1 = (unsigned short*)w;  w += (size_t)n * NF * 2;
    unsigned short* gbuf2 = (unsigned short*)w;  w += (size_t)n * NF * 2;
    float* agg   = (float*)w;  // fp32; pairs (9.6 MB) aliased here (dead before gather1 writes)
    uint2* pairs = (uint2*)agg;

    const int B = 256;

    // CSR build
    k_zero<<<(nbk + B - 1) / B, B, 0, stream>>>(bcnt, nbk);
    k_bhist<<<512, B, 0, stream>>>(dst, bcnt, E, nbk);
    k_bscan<<<1, 512, 0, stream>>>(bcnt, bbase, bcur, start, nbk, n, E);
    k_bscatter<<<(E + CHUNK - 1) / CHUNK, B, 0, stream>>>(src, dst, bcur, pairs, E, nbk);
    k_bsort<<<nbk, B, 0, stream>>>(pairs, bbase, start, adj, dis, n);

    // ----- layer 1 -----
    k_gemm<128><<<(n + 63) / 64, B, 0, stream>>>(x, W1, nullptr, dis, gbuf1, n);
    k_gather<<<(n + 3) / 4, B, 0, stream>>>(gbuf1, adj, start, dis, agg, n);

    // ----- layer 2 + head -----
    k_gemm<64><<<(n + 63) / 64, B, 0, stream>>>(agg, W2, b1, dis, gbuf2, n);
    k_gather_final<<<(n + 3) / 4, B, 0, stream>>>(gbuf2, adj, start, dis, b2, W3, b3, out, n);
}

// Round 10
// 192.954 us; speedup vs baseline: 11.4228x; 1.0040x over previous
//
#include <hip/hip_runtime.h>

#define NF 64
#define NBKMAX 512   // buckets of 256 nodes; n=100K -> 391 buckets
#define CHUNK 4096

// bf16 helpers (RNE)
__device__ __forceinline__ unsigned short f2bf(float f) {
    union { float f; unsigned u; } c; c.f = f;
    unsigned u = c.u;
    return (unsigned short)((u + 0x7FFFu + ((u >> 16) & 1u)) >> 16);
}
// packed pair of bf16 -> (lo, hi) floats
__device__ __forceinline__ float2 bfp2(unsigned v) {
    union { unsigned u; float f; } lo, hi;
    lo.u = v << 16;
    hi.u = v & 0xffff0000u;
    return make_float2(lo.f, hi.f);
}

// ---------------- bucket-radix CSR build ----------------
__global__ void k_zero(int* __restrict__ p, int m) {
    int i = blockIdx.x * blockDim.x + threadIdx.x;
    if (i < m) p[i] = 0;
}

__global__ __launch_bounds__(256) void k_bhist(const int* __restrict__ dst,
                                               int* __restrict__ bcnt, int E, int nbk) {
    __shared__ int h[NBKMAX];
    for (int i = threadIdx.x; i < nbk; i += 256) h[i] = 0;
    __syncthreads();
    int stride = gridDim.x * 256;
    for (int i = blockIdx.x * 256 + threadIdx.x; i < E; i += stride)
        atomicAdd(&h[((unsigned)dst[i]) >> 8], 1);
    __syncthreads();
    for (int i = threadIdx.x; i < nbk; i += 256) {
        int c = h[i];
        if (c) atomicAdd(&bcnt[i], c);
    }
}

__global__ __launch_bounds__(512) void k_bscan(const int* __restrict__ bcnt,
                                               int* __restrict__ bbase, int* __restrict__ bcur,
                                               int* __restrict__ start, int nbk, int n, int E) {
    __shared__ int s[512];
    int t = threadIdx.x;
    int v = (t < nbk) ? bcnt[t] : 0;
    s[t] = v; __syncthreads();
    for (int off = 1; off < 512; off <<= 1) {
        int u = (t >= off) ? s[t - off] : 0;
        __syncthreads();
        s[t] += u;
        __syncthreads();
    }
    int exc = s[t] - v;
    if (t < nbk) { bbase[t] = exc; bcur[t] = exc; }
    if (t == 0) { bbase[nbk] = E; start[n] = E; }
}

__global__ __launch_bounds__(256) void k_bscatter(const int* __restrict__ src,
                                                  const int* __restrict__ dst,
                                                  int* __restrict__ bcur,
                                                  uint2* __restrict__ pairs, int E, int nbk) {
    __shared__ int hist[NBKMAX];
    __shared__ int base[NBKMAX];
    __shared__ uint2 stage[CHUNK];
    int e0 = blockIdx.x * CHUNK;
    int cnt = E - e0; if (cnt > CHUNK) cnt = CHUNK;
    for (int i = threadIdx.x; i < nbk; i += 256) hist[i] = 0;
    __syncthreads();
    for (int i = threadIdx.x; i < cnt; i += 256) {
        int s = src[e0 + i], d = dst[e0 + i];
        stage[i] = make_uint2((unsigned)s, (unsigned)d);
        atomicAdd(&hist[((unsigned)d) >> 8], 1);
    }
    __syncthreads();
    for (int i = threadIdx.x; i < nbk; i += 256) {
        int c = hist[i];
        base[i] = c ? atomicAdd(&bcur[i], c) : 0;
        hist[i] = 0;   // reuse as local cursor
    }
    __syncthreads();
    for (int i = threadIdx.x; i < cnt; i += 256) {
        uint2 p = stage[i];
        int b = p.y >> 8;
        int off = atomicAdd(&hist[b], 1);
        pairs[base[b] + off] = p;
    }
}

__global__ __launch_bounds__(256) void k_bsort(const uint2* __restrict__ pairs,
                                               const int* __restrict__ bbase,
                                               int* __restrict__ start, int* __restrict__ adj,
                                               float* __restrict__ dis, int n) {
    __shared__ int cnt[256];
    __shared__ int cur[256];
    int b  = blockIdx.x;
    int nb = b << 8;
    int nn = n - nb; if (nn > 256) nn = 256;
    int eb = bbase[b];
    int ec = bbase[b + 1] - eb;
    int t  = threadIdx.x;
    cnt[t] = 0;
    __syncthreads();
    for (int i = t; i < ec; i += 256)
        atomicAdd(&cnt[pairs[eb + i].y & 255], 1);
    __syncthreads();
    int v = cnt[t];
    __syncthreads();
    for (int off = 1; off < 256; off <<= 1) {
        int u = (t >= off) ? cnt[t - off] : 0;
        __syncthreads();
        cnt[t] += u;
        __syncthreads();
    }
    int exc = cnt[t] - v;
    if (t < nn) {
        start[nb + t] = eb + exc;
        dis[nb + t]   = rsqrtf((float)(v + 1));
    }
    cur[t] = exc;
    __syncthreads();
    for (int i = t; i < ec; i += 256) {
        uint2 p = pairs[eb + i];
        int off = atomicAdd(&cur[p.y & 255], 1);
        adj[eb + off] = (int)p.x;
    }
}

// ---------------- GEMM: gbf16[n,64] = (act(A[n,K]) @ W[K,64]) * dis[row] ----------------
#define KT 32
__device__ __forceinline__ int swz(int kk, int r) {          // rho(k) = (5*(k>>2)+(k&3))&7
    int rho = (5 * (kk >> 2) + (kk & 3)) & 7;
    return kk * 64 + ((r + 4 * rho) & 63);
}

template<int K>
__global__ __launch_bounds__(256) void k_gemm(const float* __restrict__ A,
                                              const float* __restrict__ W,
                                              const float* __restrict__ bias_in,
                                              const float* __restrict__ dis,
                                              unsigned short* __restrict__ out, int n) {
    __shared__ float sW[KT * NF];    // 8 KB
    __shared__ float sxT[KT * 64];   // 8 KB, swizzled [k][r]
    const int tid = threadIdx.x;
    const int row_base = blockIdx.x * 64;
    const int tx = tid & 15, ty = tid >> 4;
    const int c0 = tx * 4, r0 = ty * 4;
    float acc[4][4] = {{0.f}};

    for (int kt = 0; kt < K; kt += KT) {
        __syncthreads();
        for (int i = tid * 4; i < KT * NF; i += 256 * 4)
            *(float4*)&sW[i] = *(const float4*)&W[kt * NF + i];
        #pragma unroll
        for (int it = 0; it < 2; ++it) {
            int v  = tid + it * 256;
            int r  = v >> 3;
            int kv = v & 7;
            int rg = row_base + r;
            float4 val = make_float4(0.f, 0.f, 0.f, 0.f);
            if (rg < n) val = *(const float4*)&A[(size_t)rg * K + kt + kv * 4];
            if (bias_in) {
                val.x = fmaxf(val.x + bias_in[kt + kv * 4 + 0], 0.f);
                val.y = fmaxf(val.y + bias_in[kt + kv * 4 + 1], 0.f);
                val.z = fmaxf(val.z + bias_in[kt + kv * 4 + 2], 0.f);
                val.w = fmaxf(val.w + bias_in[kt + kv * 4 + 3], 0.f);
            }
            const float vs[4] = {val.x, val.y, val.z, val.w};
            #pragma unroll
            for (int c = 0; c < 4; ++c)
                sxT[swz(kv * 4 + c, r)] = vs[c];
        }
        __syncthreads();

        #pragma unroll
        for (int kk = 0; kk < KT; ++kk) {
            const float4 xv = *(const float4*)&sxT[swz(kk, r0)];
            const float4 wv = *(const float4*)&sW[kk * 64 + c0];
            const float xs[4] = {xv.x, xv.y, xv.z, xv.w};
            const float ws[4] = {wv.x, wv.y, wv.z, wv.w};
            #pragma unroll
            for (int i = 0; i < 4; ++i)
                #pragma unroll
                for (int j = 0; j < 4; ++j)
                    acc[i][j] += xs[i] * ws[j];
        }
    }

    #pragma unroll
    for (int i = 0; i < 4; ++i) {
        int r = row_base + r0 + i;
        if (r < n) {
            float sc = dis[r];
            ushort4 o;
            o.x = f2bf(acc[i][0] * sc);
            o.y = f2bf(acc[i][1] * sc);
            o.z = f2bf(acc[i][2] * sc);
            o.w = f2bf(acc[i][3] * sc);
            *(ushort4*)&out[(size_t)r * NF + c0] = o;
        }
    }
}

// ---------------- gather v4: 16 lanes per node, 4 nodes per wave --------------------
// Lane fl owns features 4fl..4fl+3 (one uint2 = 8B per edge-row; 16 lanes = 128B row).
// No cross-lane reduction for aggregation. adj loaded 16-at-a-time per group and
// broadcast via __shfl whose source lane is always within the same active group.
__global__ __launch_bounds__(256) void k_gather(const unsigned short* __restrict__ g,
                                                const int* __restrict__ adj,
                                                const int* __restrict__ start,
                                                const float* __restrict__ dis,
                                                float* __restrict__ out, int n) {
    int node = blockIdx.x * 16 + (threadIdx.x >> 4);
    int fl   = threadIdx.x & 15;
    int gb   = threadIdx.x & 48;   // group base lane within wave (g16*16)
    if (node >= n) return;
    int s = start[node], e = start[node + 1];
    uint2 v = *(const uint2*)&g[(size_t)node * NF + fl * 4];   // self-loop
    float2 pa = bfp2(v.x), pb = bfp2(v.y);
    float4 acc = make_float4(pa.x, pa.y, pb.x, pb.y);
    for (int base = s; base < e; base += 16) {
        int m = e - base; if (m > 16) m = 16;
        int idx = (fl < m) ? adj[base + fl] : 0;
        for (int j = 0; j < m; ++j) {
            int u = __shfl(idx, gb + j);   // source lane in own (active) group
            uint2 w = *(const uint2*)&g[(size_t)u * NF + fl * 4];
            float2 q0 = bfp2(w.x), q1 = bfp2(w.y);
            acc.x += q0.x; acc.y += q0.y; acc.z += q1.x; acc.w += q1.y;
        }
    }
    float sc = dis[node];
    *(float4*)&out[(size_t)node * NF + fl * 4] =
        make_float4(acc.x * sc, acc.y * sc, acc.z * sc, acc.w * sc);
}

// ---------------- gather v4 + head fused ----------------
__global__ __launch_bounds__(256) void k_gather_final(const unsigned short* __restrict__ g,
                                                      const int* __restrict__ adj,
                                                      const int* __restrict__ start,
                                                      const float* __restrict__ dis,
                                                      const float* __restrict__ b2,
                                                      const float* __restrict__ W3,
                                                      const float* __restrict__ b3,
                                                      float* __restrict__ out, int n) {
    int node = blockIdx.x * 16 + (threadIdx.x >> 4);
    int fl   = threadIdx.x & 15;
    int gb   = threadIdx.x & 48;
    if (node >= n) return;
    int s = start[node], e = start[node + 1];
    uint2 v = *(const uint2*)&g[(size_t)node * NF + fl * 4];
    float2 pa = bfp2(v.x), pb = bfp2(v.y);
    float4 acc = make_float4(pa.x, pa.y, pb.x, pb.y);
    for (int base = s; base < e; base += 16) {
        int m = e - base; if (m > 16) m = 16;
        int idx = (fl < m) ? adj[base + fl] : 0;
        for (int j = 0; j < m; ++j) {
            int u = __shfl(idx, gb + j);
            uint2 w = *(const uint2*)&g[(size_t)u * NF + fl * 4];
            float2 q0 = bfp2(w.x), q1 = bfp2(w.y);
            acc.x += q0.x; acc.y += q0.y; acc.z += q1.x; acc.w += q1.y;
        }
    }
    float sc = dis[node];
    const float4 bb = *(const float4*)&b2[fl * 4];
    const float4 ww = *(const float4*)&W3[fl * 4];
    float r = fmaxf(acc.x * sc + bb.x, 0.f) * ww.x
            + fmaxf(acc.y * sc + bb.y, 0.f) * ww.y
            + fmaxf(acc.z * sc + bb.z, 0.f) * ww.z
            + fmaxf(acc.w * sc + bb.w, 0.f) * ww.w;
    #pragma unroll
    for (int off = 8; off > 0; off >>= 1) r += __shfl_down(r, off, 16);
    if (fl == 0) out[node] = r + b3[0];
}

extern "C" void kernel_launch(void* const* d_in, const int* in_sizes, int n_in,
                              void* d_out, int out_size, void* d_ws, size_t ws_size,
                              hipStream_t stream) {
    const float* x  = (const float*)d_in[0];
    const int*   ei = (const int*)d_in[1];   // int32 (JAX x64-disabled)
    const float* W1 = (const float*)d_in[2];
    const float* b1 = (const float*)d_in[3];
    const float* W2 = (const float*)d_in[4];
    const float* b2 = (const float*)d_in[5];
    const float* W3 = (const float*)d_in[6];
    const float* b3 = (const float*)d_in[7];
    float* out = (float*)d_out;

    const int n = out_size;           // 100000
    const int E = in_sizes[1] / 2;    // 1200000
    const int* src = ei;
    const int* dst = ei + E;
    const int ns  = (n + 255) & ~255;
    const int nbk = (n + 255) >> 8;   // 391

    char* w = (char*)d_ws;
    float* dis   = (float*)w;  w += (size_t)ns * 4;
    int*   start = (int*)w;    w += (size_t)(ns + 256) * 4;
    int*   adj   = (int*)w;    w += (size_t)E * 4;
    int*   bcnt  = (int*)w;    w += NBKMAX * 4;
    int*   bbase = (int*)w;    w += (NBKMAX + 1) * 4;
    int*   bcur  = (int*)w;    w += NBKMAX * 4;
    unsigned short* gbuf1 = (unsigned short*)w;  w += (size_t)n * NF * 2;
    unsigned short* gbuf2 = (unsigned short*)w;  w += (size_t)n * NF * 2;
    float* agg   = (float*)w;  // fp32; pairs (9.6 MB) aliased here (dead before gather1 writes)
    uint2* pairs = (uint2*)agg;

    const int B = 256;

    // CSR build
    k_zero<<<(nbk + B - 1) / B, B, 0, stream>>>(bcnt, nbk);
    k_bhist<<<512, B, 0, stream>>>(dst, bcnt, E, nbk);
    k_bscan<<<1, 512, 0, stream>>>(bcnt, bbase, bcur, start, nbk, n, E);
    k_bscatter<<<(E + CHUNK - 1) / CHUNK, B, 0, stream>>>(src, dst, bcur, pairs, E, nbk);
    k_bsort<<<nbk, B, 0, stream>>>(pairs, bbase, start, adj, dis, n);

    // ----- layer 1 -----
    k_gemm<128><<<(n + 63) / 64, B, 0, stream>>>(x, W1, nullptr, dis, gbuf1, n);
    k_gather<<<(n + 15) / 16, B, 0, stream>>>(gbuf1, adj, start, dis, agg, n);

    // ----- layer 2 + head -----
    k_gemm<64><<<(n + 63) / 64, B, 0, stream>>>(agg, W2, b1, dis, gbuf2, n);
    k_gather_final<<<(n + 15) / 16, B, 0, stream>>>(gbuf2, adj, start, dis, b2, W3, b3, out, n);
}